// Round 2
// baseline (1079.283 us; speedup 1.0000x reference)
//
#include <hip/hip_runtime.h>
#include <hip/hip_bf16.h>

#define NCH 256      // C
#define NHD 8        // heads
#define HD 32        // head dim
#define NPIX 2304    // 48*48
#define H1DIM 512

// ---------------- generic 1x1 conv (channel GEMM) ----------------
// out[b, ob+o, n] = act( bias[o] + resid? + sum_c w[(ob+o)*IC + c] * (in1[b,c,n] + in2?[b,c,n]) )
// grid: (3 n-tiles of 768, OC/8, B); block 256; 3 pixels/thread, 8 out-ch/block.
template <bool ADD2, bool RESID, bool SILU>
__global__ __launch_bounds__(256) void conv1x1_k(
    const float* __restrict__ in1, const float* __restrict__ in2,
    const float* __restrict__ resid,
    const float* __restrict__ w, const float* __restrict__ bias,
    float* __restrict__ out, int IC) {
    const int tid = threadIdx.x;
    const int n0  = blockIdx.x * 768;
    const int ob  = blockIdx.y * 8;
    const int b   = blockIdx.z;
    const int OC  = gridDim.y * 8;

    // weights transposed in LDS: w_lds[c*8 + o], read as float4 broadcast
    __shared__ __align__(16) float w_lds[8 * 512];
    for (int idx = tid; idx < IC * 8; idx += 256) {
        int o = idx & 7, c = idx >> 3;
        w_lds[c * 8 + o] = w[(size_t)(ob + o) * IC + c];
    }
    __syncthreads();

    float acc[8][3] = {};
    const size_t inoff = (size_t)b * IC * NPIX + n0 + tid;
    const float* p1 = in1 + inoff;
    const float* p2 = ADD2 ? (in2 + inoff) : nullptr;

#pragma unroll 2
    for (int c = 0; c < IC; ++c) {
        float xv[3];
#pragma unroll
        for (int j = 0; j < 3; ++j) {
            float t = p1[(size_t)c * NPIX + j * 256];
            if constexpr (ADD2) t += p2[(size_t)c * NPIX + j * 256];
            xv[j] = t;
        }
        float4 w0 = *(const float4*)&w_lds[c * 8];
        float4 w1 = *(const float4*)&w_lds[c * 8 + 4];
        const float wv[8] = {w0.x, w0.y, w0.z, w0.w, w1.x, w1.y, w1.z, w1.w};
#pragma unroll
        for (int o = 0; o < 8; ++o)
#pragma unroll
            for (int j = 0; j < 3; ++j) acc[o][j] += wv[o] * xv[j];
    }

#pragma unroll
    for (int o = 0; o < 8; ++o) {
        float bb = bias[ob + o];
        size_t obase = ((size_t)b * OC + ob + o) * NPIX + n0 + tid;
#pragma unroll
        for (int j = 0; j < 3; ++j) {
            float r = acc[o][j] + bb;
            if constexpr (RESID) r += resid[obase + j * 256];
            if constexpr (SILU) r = r / (1.f + __expf(-r));
            out[obase + j * 256] = r;
        }
    }
}

// ---------------- depthwise 7x7, SAME, per (b,c) plane ----------------
__global__ __launch_bounds__(256) void dwconv_k(const float* __restrict__ vb,
                                                const float* __restrict__ pw,
                                                const float* __restrict__ pb,
                                                float* __restrict__ pe) {
    const int c = blockIdx.x, b = blockIdx.y, tid = threadIdx.x;
    __shared__ float plane[NPIX];
    __shared__ float wk[49];
    const size_t base = ((size_t)b * NCH + c) * NPIX;
    for (int i = tid; i < NPIX; i += 256) plane[i] = vb[base + i];
    if (tid < 49) wk[tid] = pw[c * 49 + tid];
    float bb = pb[c];
    __syncthreads();
    for (int p = tid; p < NPIX; p += 256) {
        int y = p / 48, x = p - y * 48;
        float s = bb;
#pragma unroll
        for (int ky = 0; ky < 7; ++ky) {
            int yy = y + ky - 3;
            if ((unsigned)yy < 48u) {
#pragma unroll
                for (int kx = 0; kx < 7; ++kx) {
                    int xx = x + kx - 3;
                    if ((unsigned)xx < 48u) s += wk[ky * 7 + kx] * plane[yy * 48 + xx];
                }
            }
        }
        pe[base + p] = s;
    }
}

// ---------------- flash attention, f32 ----------------
// block = 256 threads = 8 query-groups of 32 lanes; thread (qi,g): query nb+qi, dim d=g.
// grid (N/8, NH, B)
__global__ __launch_bounds__(256) void attn_k(const float* __restrict__ qk,
                                              const float* __restrict__ v,
                                              float* __restrict__ o) {
    const int tid = threadIdx.x;
    const int qi = tid >> 5, g = tid & 31;
    const int nb = blockIdx.x * 8;
    const int h = blockIdx.y, b = blockIdx.z;
    const int n = nb + qi;

    const float* qp = qk + ((size_t)b * 512 + h * 64) * NPIX;       // q rows: ch h*64 + d
    const float* kp = qp + (size_t)32 * NPIX;                        // k rows: ch h*64+32+d
    const float* vp = v + ((size_t)b * NCH + h * 32) * NPIX;

    __shared__ float q_s[8 * 32];
    __shared__ float k_s[32 * 65];                 // pad 65: conflict-free column reads
    __shared__ __align__(16) float v_s[32 * 68];   // pad 68: 16B-aligned rows
    __shared__ __align__(16) float p_s[8 * 64];

    q_s[tid] = qp[(size_t)(tid & 31) * NPIX + nb + (tid >> 5)] * 0.17677669529663689f;
    __syncthreads();

    float qreg[32];
#pragma unroll
    for (int d = 0; d < 32; ++d) qreg[d] = q_s[qi * 32 + d];

    float m_run = -1e30f, l_run = 0.f, oacc = 0.f;

    for (int mb = 0; mb < NPIX; mb += 64) {
        for (int idx = tid; idx < 2048; idx += 256) {
            int r = idx >> 6, cm = idx & 63;
            float kv = kp[(size_t)r * NPIX + mb + cm];
            float vv = vp[(size_t)r * NPIX + mb + cm];
            k_s[r * 65 + cm] = kv;
            v_s[r * 68 + cm] = vv;
        }
        __syncthreads();

        float s1 = 0.f, s2 = 0.f;
#pragma unroll 8
        for (int d = 0; d < 32; ++d) {
            s1 += qreg[d] * k_s[d * 65 + g];
            s2 += qreg[d] * k_s[d * 65 + g + 32];
        }
        float mx = fmaxf(s1, s2);
#pragma unroll
        for (int off = 16; off; off >>= 1) mx = fmaxf(mx, __shfl_xor(mx, off, 32));
        float mnew = fmaxf(m_run, mx);
        float p1 = __expf(s1 - mnew), p2 = __expf(s2 - mnew);
        float alpha = __expf(m_run - mnew);
        float ps = p1 + p2;
#pragma unroll
        for (int off = 16; off; off >>= 1) ps += __shfl_xor(ps, off, 32);
        l_run = l_run * alpha + ps;
        m_run = mnew;
        oacc *= alpha;
        p_s[qi * 64 + g] = p1;
        p_s[qi * 64 + g + 32] = p2;
        __syncthreads();

        const float4* prow = (const float4*)&p_s[qi * 64];
        const float4* vrow = (const float4*)&v_s[g * 68];
#pragma unroll 4
        for (int mp = 0; mp < 16; ++mp) {
            float4 pv = prow[mp];
            float4 vv = vrow[mp];
            oacc += pv.x * vv.x + pv.y * vv.y + pv.z * vv.z + pv.w * vv.w;
        }
        __syncthreads();
    }
    o[((size_t)b * NCH + h * 32 + g) * NPIX + n] = oacc / l_run;
}

extern "C" void kernel_launch(void* const* d_in, const int* in_sizes, int n_in,
                              void* d_out, int out_size, void* d_ws, size_t ws_size,
                              hipStream_t stream) {
    const float* x    = (const float*)d_in[0];
    const float* qk_w = (const float*)d_in[1];
    const float* qk_b = (const float*)d_in[2];
    const float* v_w  = (const float*)d_in[3];
    const float* v_b  = (const float*)d_in[4];
    const float* pe_w = (const float*)d_in[5];
    const float* pe_b = (const float*)d_in[6];
    const float* pj_w = (const float*)d_in[7];
    const float* pj_b = (const float*)d_in[8];
    const float* f1_w = (const float*)d_in[9];
    const float* f1_b = (const float*)d_in[10];
    const float* f2_w = (const float*)d_in[11];
    const float* f2_b = (const float*)d_in[12];
    float* out = (float*)d_out;

    const int B = 2;
    const size_t plane = (size_t)NCH * NPIX;   // 589824 elements

    float* ws    = (float*)d_ws;
    float* qk_bf = ws;                         //  B*2*plane  (9.4 MB)
    float* v_bu  = qk_bf + 2 * B * plane;      //  B*plane
    float* pe_bu = v_bu + B * plane;           //  B*plane
    float* o_bu  = pe_bu + B * plane;          //  B*plane
    float* x1_bu = o_bu + B * plane;           //  B*plane
    float* h_bu  = qk_bf;                      //  alias: qk dead after attention

    // qk = conv1x1(x; qk_w, qk_b)  -> (B, 512, N)
    conv1x1_k<false, false, false><<<dim3(3, 64, B), 256, 0, stream>>>(
        x, nullptr, nullptr, qk_w, qk_b, qk_bf, NCH);
    // v_full = conv1x1(x; v_w, v_b) -> (B, 256, N)
    conv1x1_k<false, false, false><<<dim3(3, 32, B), 256, 0, stream>>>(
        x, nullptr, nullptr, v_w, v_b, v_bu, NCH);
    // pe = dwconv7x7(v_full) + pe_b
    dwconv_k<<<dim3(NCH, B), 256, 0, stream>>>(v_bu, pe_w, pe_b, pe_bu);
    // o = attention(q, k, v)
    attn_k<<<dim3(NPIX / 8, NHD, B), 256, 0, stream>>>(qk_bf, v_bu, o_bu);
    // x1 = x + proj(o + pe)
    conv1x1_k<true, true, false><<<dim3(3, 32, B), 256, 0, stream>>>(
        o_bu, pe_bu, x, pj_w, pj_b, x1_bu, NCH);
    // h = silu(fc1(x1))   (overwrites qk buffer)
    conv1x1_k<false, false, true><<<dim3(3, 64, B), 256, 0, stream>>>(
        x1_bu, nullptr, nullptr, f1_w, f1_b, h_bu, NCH);
    // out = x1 + fc2(h)
    conv1x1_k<false, true, false><<<dim3(3, 32, B), 256, 0, stream>>>(
        h_bu, nullptr, x1_bu, f2_w, f2_b, out, H1DIM);
}

// Round 3
// 494.969 us; speedup vs baseline: 2.1805x; 2.1805x over previous
//
#include <hip/hip_runtime.h>
#include <hip/hip_bf16.h>

#define NCH 256      // C
#define NHD 8        // heads
#define HD 32        // head dim
#define NPIX 2304    // 48*48
#define H1DIM 512

typedef __attribute__((ext_vector_type(8))) __bf16 bf16x8;
typedef __attribute__((ext_vector_type(4))) float f32x4;

// ---------------- generic 1x1 conv (channel GEMM) ----------------
template <bool ADD2, bool RESID, bool SILU>
__global__ __launch_bounds__(256) void conv1x1_k(
    const float* __restrict__ in1, const float* __restrict__ in2,
    const float* __restrict__ resid,
    const float* __restrict__ w, const float* __restrict__ bias,
    float* __restrict__ out, int IC) {
    const int tid = threadIdx.x;
    const int n0  = blockIdx.x * 768;
    const int ob  = blockIdx.y * 8;
    const int b   = blockIdx.z;
    const int OC  = gridDim.y * 8;

    __shared__ __align__(16) float w_lds[8 * 512];
    for (int idx = tid; idx < IC * 8; idx += 256) {
        int o = idx & 7, c = idx >> 3;
        w_lds[c * 8 + o] = w[(size_t)(ob + o) * IC + c];
    }
    __syncthreads();

    float acc[8][3] = {};
    const size_t inoff = (size_t)b * IC * NPIX + n0 + tid;
    const float* p1 = in1 + inoff;
    const float* p2 = ADD2 ? (in2 + inoff) : nullptr;

#pragma unroll 2
    for (int c = 0; c < IC; ++c) {
        float xv[3];
#pragma unroll
        for (int j = 0; j < 3; ++j) {
            float t = p1[(size_t)c * NPIX + j * 256];
            if constexpr (ADD2) t += p2[(size_t)c * NPIX + j * 256];
            xv[j] = t;
        }
        float4 w0 = *(const float4*)&w_lds[c * 8];
        float4 w1 = *(const float4*)&w_lds[c * 8 + 4];
        const float wv[8] = {w0.x, w0.y, w0.z, w0.w, w1.x, w1.y, w1.z, w1.w};
#pragma unroll
        for (int o = 0; o < 8; ++o)
#pragma unroll
            for (int j = 0; j < 3; ++j) acc[o][j] += wv[o] * xv[j];
    }

#pragma unroll
    for (int o = 0; o < 8; ++o) {
        float bb = bias[ob + o];
        size_t obase = ((size_t)b * OC + ob + o) * NPIX + n0 + tid;
#pragma unroll
        for (int j = 0; j < 3; ++j) {
            float r = acc[o][j] + bb;
            if constexpr (RESID) r += resid[obase + j * 256];
            if constexpr (SILU) r = r / (1.f + __expf(-r));
            out[obase + j * 256] = r;
        }
    }
}

// ---------------- depthwise 7x7, SAME, per (b,c) plane ----------------
__global__ __launch_bounds__(256) void dwconv_k(const float* __restrict__ vb,
                                                const float* __restrict__ pw,
                                                const float* __restrict__ pb,
                                                float* __restrict__ pe) {
    const int c = blockIdx.x, b = blockIdx.y, tid = threadIdx.x;
    __shared__ float plane[NPIX];
    __shared__ float wk[49];
    const size_t base = ((size_t)b * NCH + c) * NPIX;
    for (int i = tid; i < NPIX; i += 256) plane[i] = vb[base + i];
    if (tid < 49) wk[tid] = pw[c * 49 + tid];
    float bb = pb[c];
    __syncthreads();
    for (int p = tid; p < NPIX; p += 256) {
        int y = p / 48, x = p - y * 48;
        float s = bb;
#pragma unroll
        for (int ky = 0; ky < 7; ++ky) {
            int yy = y + ky - 3;
            if ((unsigned)yy < 48u) {
#pragma unroll
                for (int kx = 0; kx < 7; ++kx) {
                    int xx = x + kx - 3;
                    if ((unsigned)xx < 48u) s += wk[ky * 7 + kx] * plane[yy * 48 + xx];
                }
            }
        }
        pe[base + p] = s;
    }
}

// ---------------- qk prep: transpose [d][n] -> [n][d], scale q, cast bf16 ----
// grid (NPIX/64, NH, B), block 256. Per block: 64ch x 64n tile of one head.
__global__ __launch_bounds__(256) void qk_prep_k(const float* __restrict__ qk,
                                                 __bf16* __restrict__ Qb,
                                                 __bf16* __restrict__ Kb) {
    const int tid = threadIdx.x;
    const int n0 = blockIdx.x * 64;
    const int h = blockIdx.y, b = blockIdx.z;
    const int bh = b * NHD + h;
    __shared__ float tile[64][65];
    const float* src = qk + ((size_t)b * 512 + h * 64) * NPIX + n0;
#pragma unroll
    for (int i = 0; i < 16; ++i) {
        int idx = tid + i * 256;
        int r = idx >> 6, c = idx & 63;
        tile[r][c] = src[(size_t)r * NPIX + c];
    }
    __syncthreads();
    const float scale = 0.17677669529663689f;  // hd^-0.5
#pragma unroll
    for (int half = 0; half < 2; ++half) {
        __bf16* dst = (half ? Kb : Qb) + ((size_t)bh * NPIX + n0) * 32;
        float sc = half ? 1.f : scale;
#pragma unroll
        for (int i = 0; i < 4; ++i) {
            int pidx = tid + i * 256;        // 0..1023
            int nn = pidx >> 4, dp = (pidx & 15) * 2;
            union { __bf16 h2[2]; unsigned u; } pk;
            pk.h2[0] = (__bf16)(tile[half * 32 + dp][nn] * sc);
            pk.h2[1] = (__bf16)(tile[half * 32 + dp + 1][nn] * sc);
            *(unsigned*)&dst[(size_t)nn * 32 + dp] = pk.u;
        }
    }
}

// ---------------- v cast: f32 -> bf16, layout unchanged [bh][d][n] ----------
__global__ __launch_bounds__(256) void v_cast_k(const float* __restrict__ in,
                                                __bf16* __restrict__ out, int n4) {
    int i = blockIdx.x * 256 + threadIdx.x;
    if (i < n4) {
        float4 v = ((const float4*)in)[i];
        union { __bf16 h[4]; uint2 u; } pk;
        pk.h[0] = (__bf16)v.x; pk.h[1] = (__bf16)v.y;
        pk.h[2] = (__bf16)v.z; pk.h[3] = (__bf16)v.w;
        ((uint2*)out)[i] = pk.u;
    }
}

// ---------------- MFMA flash attention ----------------
// block = 4 independent waves; wave owns 16 queries. grid (NPIX/64, NH, B).
// Qb/Kb: [bh][n][32] bf16 (Q pre-scaled). Vb: [bh][32][n] bf16. o: [b][256][n] f32.
__global__ __launch_bounds__(256) void attn_mfma_k(const __bf16* __restrict__ Qb,
                                                   const __bf16* __restrict__ Kb,
                                                   const __bf16* __restrict__ Vb,
                                                   float* __restrict__ o) {
    const int tid = threadIdx.x;
    const int wave = tid >> 6;
    const int lane = tid & 63;
    const int l16 = lane & 15;
    const int quad = lane >> 4;
    const int nb = blockIdx.x * 64;
    const int h = blockIdx.y, b = blockIdx.z;
    const int bh = b * NHD + h;

    // per-wave P buffer: 16 q x 64 keys, row stride 72 (16B-aligned, b128 reads 2-way-free)
    __shared__ __bf16 p_lds[4][16][72];

    // A frag (held all kernel): Q[m=l16][k=quad*8+j]
    const __bf16* qptr = Qb + ((size_t)bh * NPIX + nb + wave * 16 + l16) * 32 + quad * 8;
    bf16x8 a_q = *(const bf16x8*)qptr;

    f32x4 o_acc0 = {0.f, 0.f, 0.f, 0.f}, o_acc1 = {0.f, 0.f, 0.f, 0.f};
    float m_run[4], l_run[4];
#pragma unroll
    for (int r = 0; r < 4; ++r) { m_run[r] = -1e30f; l_run[r] = 0.f; }

    const __bf16* kbase = Kb + (size_t)bh * NPIX * 32;
    const __bf16* vbase = Vb + (size_t)bh * 32 * NPIX;

    for (int mc = 0; mc < NPIX; mc += 64) {
        // S[q=quad*4+r][key=kb*16+l16] : 4 mfma, B[k=d][n=key] from Kb[key][d]
        f32x4 s[4];
#pragma unroll
        for (int kb = 0; kb < 4; ++kb) {
            bf16x8 b_k = *(const bf16x8*)(kbase + (size_t)(mc + kb * 16 + l16) * 32 + quad * 8);
            f32x4 z = {0.f, 0.f, 0.f, 0.f};
            s[kb] = __builtin_amdgcn_mfma_f32_16x16x32_bf16(a_q, b_k, z, 0, 0, 0);
        }
        // online softmax per query row
#pragma unroll
        for (int r = 0; r < 4; ++r) {
            float m0 = fmaxf(fmaxf(s[0][r], s[1][r]), fmaxf(s[2][r], s[3][r]));
#pragma unroll
            for (int off = 1; off < 16; off <<= 1) m0 = fmaxf(m0, __shfl_xor(m0, off));
            float mnew = fmaxf(m_run[r], m0);
            float alpha = __expf(m_run[r] - mnew);
            m_run[r] = mnew;
            float ps = 0.f;
#pragma unroll
            for (int kb = 0; kb < 4; ++kb) {
                float pv = __expf(s[kb][r] - mnew);
                p_lds[wave][quad * 4 + r][kb * 16 + l16] = (__bf16)pv;
                ps += pv;
            }
#pragma unroll
            for (int off = 1; off < 16; off <<= 1) ps += __shfl_xor(ps, off);
            l_run[r] = l_run[r] * alpha + ps;
            o_acc0[r] *= alpha;
            o_acc1[r] *= alpha;
        }
        // PV: A = P[q=l16][key], B[k=key][n=d] from Vb[d][key]
#pragma unroll
        for (int kh = 0; kh < 2; ++kh) {
            bf16x8 a_p = *(const bf16x8*)&p_lds[wave][l16][kh * 32 + quad * 8];
            const __bf16* vp0 = vbase + (size_t)l16 * NPIX + mc + kh * 32 + quad * 8;
            bf16x8 b_v0 = *(const bf16x8*)vp0;
            bf16x8 b_v1 = *(const bf16x8*)(vp0 + (size_t)16 * NPIX);
            o_acc0 = __builtin_amdgcn_mfma_f32_16x16x32_bf16(a_p, b_v0, o_acc0, 0, 0, 0);
            o_acc1 = __builtin_amdgcn_mfma_f32_16x16x32_bf16(a_p, b_v1, o_acc1, 0, 0, 0);
        }
    }

    const int qrow = nb + wave * 16 + quad * 4;
#pragma unroll
    for (int r = 0; r < 4; ++r) {
        float inv = 1.f / l_run[r];
        o[((size_t)b * NCH + h * HD + l16) * NPIX + qrow + r]      = o_acc0[r] * inv;
        o[((size_t)b * NCH + h * HD + 16 + l16) * NPIX + qrow + r] = o_acc1[r] * inv;
    }
}

extern "C" void kernel_launch(void* const* d_in, const int* in_sizes, int n_in,
                              void* d_out, int out_size, void* d_ws, size_t ws_size,
                              hipStream_t stream) {
    const float* x    = (const float*)d_in[0];
    const float* qk_w = (const float*)d_in[1];
    const float* qk_b = (const float*)d_in[2];
    const float* v_w  = (const float*)d_in[3];
    const float* v_b  = (const float*)d_in[4];
    const float* pe_w = (const float*)d_in[5];
    const float* pe_b = (const float*)d_in[6];
    const float* pj_w = (const float*)d_in[7];
    const float* pj_b = (const float*)d_in[8];
    const float* f1_w = (const float*)d_in[9];
    const float* f1_b = (const float*)d_in[10];
    const float* f2_w = (const float*)d_in[11];
    const float* f2_b = (const float*)d_in[12];
    float* out = (float*)d_out;

    const int B = 2;
    const size_t plane = (size_t)NCH * NPIX;   // 589824 elements

    float* ws    = (float*)d_ws;
    float* qk_bf = ws;                         //  B*2*plane f32
    float* v_bu  = qk_bf + 2 * B * plane;      //  B*plane f32
    float* pe_bu = v_bu + B * plane;           //  B*plane f32
    float* o_bu  = pe_bu + B * plane;          //  B*plane f32
    float* x1_bu = o_bu + B * plane;           //  B*plane f32
    float* h_bu  = qk_bf;                      //  alias: qk dead after attention
    // bf16 buffers (each B*plane bf16 = B*plane/2 floats worth)
    __bf16* Qb = (__bf16*)(x1_bu + B * plane);
    __bf16* Kb = Qb + B * plane;
    __bf16* Vb = Kb + B * plane;

    // qk = conv1x1(x; qk_w, qk_b)  -> (B, 512, N)
    conv1x1_k<false, false, false><<<dim3(3, 64, B), 256, 0, stream>>>(
        x, nullptr, nullptr, qk_w, qk_b, qk_bf, NCH);
    // v_full = conv1x1(x; v_w, v_b) -> (B, 256, N)
    conv1x1_k<false, false, false><<<dim3(3, 32, B), 256, 0, stream>>>(
        x, nullptr, nullptr, v_w, v_b, v_bu, NCH);
    // pe = dwconv7x7(v_full) + pe_b
    dwconv_k<<<dim3(NCH, B), 256, 0, stream>>>(v_bu, pe_w, pe_b, pe_bu);
    // bf16 prep for attention
    qk_prep_k<<<dim3(NPIX / 64, NHD, B), 256, 0, stream>>>(qk_bf, Qb, Kb);
    v_cast_k<<<(B * (int)plane / 4 + 255) / 256, 256, 0, stream>>>(v_bu, Vb, B * (int)plane / 4);
    // o = attention(q, k, v)  [MFMA]
    attn_mfma_k<<<dim3(NPIX / 64, NHD, B), 256, 0, stream>>>(Qb, Kb, Vb, o_bu);
    // x1 = x + proj(o + pe)
    conv1x1_k<true, true, false><<<dim3(3, 32, B), 256, 0, stream>>>(
        o_bu, pe_bu, x, pj_w, pj_b, x1_bu, NCH);
    // h = silu(fc1(x1))
    conv1x1_k<false, false, true><<<dim3(3, 64, B), 256, 0, stream>>>(
        x1_bu, nullptr, nullptr, f1_w, f1_b, h_bu, NCH);
    // out = x1 + fc2(h)
    conv1x1_k<false, true, false><<<dim3(3, 32, B), 256, 0, stream>>>(
        h_bu, nullptr, x1_bu, f2_w, f2_b, out, H1DIM);
}

// Round 4
// 291.369 us; speedup vs baseline: 3.7042x; 1.6988x over previous
//
#include <hip/hip_runtime.h>
#include <hip/hip_bf16.h>

#define NCH 256      // C
#define NHD 8        // heads
#define HD 32        // head dim
#define NPIX 2304    // 48*48
#define H1DIM 512

typedef __attribute__((ext_vector_type(8))) __bf16 bf16x8;
typedef __attribute__((ext_vector_type(4))) float f32x4;

// ---------------- weight cast f32 -> bf16 (all 5 matrices, one launch) -------
// quad-index space: Wq 32768 | Wv 16384 | Wp 16384 | W1 32768 | W2 32768 = 131072
__global__ __launch_bounds__(256) void wcast_k(
    const float* __restrict__ w0, const float* __restrict__ w1,
    const float* __restrict__ w2, const float* __restrict__ w3,
    const float* __restrict__ w4, __bf16* __restrict__ dst) {
    int i = blockIdx.x * 256 + threadIdx.x;
    const float* src; int off;
    if (i < 32768)      { src = w0; off = i; }
    else if (i < 49152) { src = w1; off = i - 32768; }
    else if (i < 65536) { src = w2; off = i - 49152; }
    else if (i < 98304) { src = w3; off = i - 65536; }
    else                { src = w4; off = i - 98304; }
    float4 v = ((const float4*)src)[off];
    union { __bf16 h[4]; uint2 u; } pk;
    pk.h[0] = (__bf16)v.x; pk.h[1] = (__bf16)v.y;
    pk.h[2] = (__bf16)v.z; pk.h[3] = (__bf16)v.w;
    ((uint2*)dst)[i] = pk.u;
}

// ---------------- NCHW f32 (+optional add) -> NHWC bf16 transpose ------------
// grid (NPIX/64, NCH/64, B), block 256
template <bool ADD>
__global__ __launch_bounds__(256) void nchw2nhwc_k(const float* __restrict__ s1,
                                                   const float* __restrict__ s2,
                                                   __bf16* __restrict__ dst) {
    const int tid = threadIdx.x;
    const int n0 = blockIdx.x * 64;
    const int c0 = blockIdx.y * 64;
    const int b = blockIdx.z;
    __shared__ float tile[64][65];
    const size_t sb = ((size_t)b * NCH + c0) * NPIX + n0;
#pragma unroll
    for (int i = 0; i < 16; ++i) {
        int idx = tid + i * 256;
        int r = idx >> 6, c = idx & 63;
        float v = s1[sb + (size_t)r * NPIX + c];
        if constexpr (ADD) v += s2[sb + (size_t)r * NPIX + c];
        tile[r][c] = v;
    }
    __syncthreads();
#pragma unroll
    for (int i = 0; i < 8; ++i) {
        int idx = tid + i * 256;
        int nn = idx >> 5, cp = (idx & 31) * 2;
        union { __bf16 h[2]; unsigned u; } pk;
        pk.h[0] = (__bf16)tile[cp][nn];
        pk.h[1] = (__bf16)tile[cp + 1][nn];
        *(unsigned*)&dst[((size_t)b * NPIX + n0 + nn) * NCH + c0 + cp] = pk.u;
    }
}

// ---------------- MFMA 1x1 conv ----------------
// C[pix][oc] = A[pix][ic] . W[oc][ic]^T, per batch. grid (NPIX/64, OC/64, B),
// block 256 = 4 waves; wave w: 16 pixels x 64 oc; no LDS, no syncthreads.
// MODE 0: qk   -> out_b NHWC bf16 [b][n][OC]
// MODE 1: v    -> out_f NCHW f32 + out_b NCHW bf16 (=V^T for attention)
// MODE 2: proj -> +resid(x,NCHW); out_f NCHW f32 (x1) + out_b NHWC bf16 (x1)
// MODE 3: fc1  -> silu; out_b NHWC bf16
// MODE 4: fc2  -> +resid(x1,NCHW); out_f NCHW f32 (final output)
template <int IC, int OC, int MODE>
__global__ __launch_bounds__(256) void convmm_k(
    const __bf16* __restrict__ A, const __bf16* __restrict__ W,
    const float* __restrict__ bias, const float* __restrict__ resid,
    float* __restrict__ out_f, __bf16* __restrict__ out_b) {
    const int tid = threadIdx.x;
    const int wave = tid >> 6, lane = tid & 63;
    const int l16 = lane & 15, quad = lane >> 4;
    const int m0 = blockIdx.x * 64 + wave * 16;
    const int oc0 = blockIdx.y * 64;
    const int b = blockIdx.z;

    const __bf16* aptr = A + ((size_t)b * NPIX + m0 + l16) * IC + quad * 8;
    const __bf16* bptr = W + ((size_t)(oc0 + l16)) * IC + quad * 8;

    f32x4 acc[4] = {{0.f,0.f,0.f,0.f},{0.f,0.f,0.f,0.f},{0.f,0.f,0.f,0.f},{0.f,0.f,0.f,0.f}};
#pragma unroll 8
    for (int k = 0; k < IC; k += 32) {
        bf16x8 af = *(const bf16x8*)(aptr + k);
#pragma unroll
        for (int t = 0; t < 4; ++t) {
            bf16x8 bf = *(const bf16x8*)(bptr + (size_t)t * 16 * IC + k);
            acc[t] = __builtin_amdgcn_mfma_f32_16x16x32_bf16(af, bf, acc[t], 0, 0, 0);
        }
    }

    const int mb = m0 + quad * 4;
#pragma unroll
    for (int t = 0; t < 4; ++t) {
        const int oc = oc0 + t * 16 + l16;
        const float bb = bias[oc];
        if constexpr (MODE == 0 || MODE == 3) {
#pragma unroll
            for (int r = 0; r < 4; ++r) {
                float v = acc[t][r] + bb;
                if constexpr (MODE == 3) v = v / (1.f + __expf(-v));
                out_b[((size_t)b * NPIX + mb + r) * OC + oc] = (__bf16)v;
            }
        } else if constexpr (MODE == 1) {
            const size_t base = ((size_t)b * OC + oc) * NPIX + mb;
            float4 vf; float* vp = &vf.x;
            union { __bf16 h[4]; uint2 u; } pk;
#pragma unroll
            for (int r = 0; r < 4; ++r) {
                float v = acc[t][r] + bb;
                vp[r] = v; pk.h[r] = (__bf16)v;
            }
            *(float4*)&out_f[base] = vf;
            *(uint2*)&out_b[base] = pk.u;
        } else if constexpr (MODE == 2) {
            const size_t base = ((size_t)b * OC + oc) * NPIX + mb;
            float4 xr = *(const float4*)&resid[base];
            const float* xp = &xr.x;
            float4 vf; float* vp = &vf.x;
#pragma unroll
            for (int r = 0; r < 4; ++r) {
                float v = acc[t][r] + bb + xp[r];
                vp[r] = v;
                out_b[((size_t)b * NPIX + mb + r) * OC + oc] = (__bf16)v;
            }
            *(float4*)&out_f[base] = vf;
        } else {  // MODE 4
            const size_t base = ((size_t)b * OC + oc) * NPIX + mb;
            float4 xr = *(const float4*)&resid[base];
            const float* xp = &xr.x;
            float4 vf; float* vp = &vf.x;
#pragma unroll
            for (int r = 0; r < 4; ++r) vp[r] = acc[t][r] + bb + xp[r];
            *(float4*)&out_f[base] = vf;
        }
    }
}

// ---------------- depthwise 7x7, SAME, per (b,c) plane ----------------
__global__ __launch_bounds__(256) void dwconv_k(const float* __restrict__ vb,
                                                const float* __restrict__ pw,
                                                const float* __restrict__ pb,
                                                float* __restrict__ pe) {
    const int c = blockIdx.x, b = blockIdx.y, tid = threadIdx.x;
    __shared__ float plane[NPIX];
    __shared__ float wk[49];
    const size_t base = ((size_t)b * NCH + c) * NPIX;
    for (int i = tid; i < NPIX; i += 256) plane[i] = vb[base + i];
    if (tid < 49) wk[tid] = pw[c * 49 + tid];
    float bb = pb[c];
    __syncthreads();
    for (int p = tid; p < NPIX; p += 256) {
        int y = p / 48, x = p - y * 48;
        float s = bb;
#pragma unroll
        for (int ky = 0; ky < 7; ++ky) {
            int yy = y + ky - 3;
            if ((unsigned)yy < 48u) {
#pragma unroll
                for (int kx = 0; kx < 7; ++kx) {
                    int xx = x + kx - 3;
                    if ((unsigned)xx < 48u) s += wk[ky * 7 + kx] * plane[yy * 48 + xx];
                }
            }
        }
        pe[base + p] = s;
    }
}

// ---------------- MFMA flash attention ----------------
// Q,K read directly from qkb NHWC bf16 [b][n][512] (scale applied to S).
// Vb: NCHW bf16 = [bh][d][n]. o: NCHW f32. grid (NPIX/64, NH, B), 4 waves.
__global__ __launch_bounds__(256) void attn_mfma_k(const __bf16* __restrict__ qkb,
                                                   const __bf16* __restrict__ Vb,
                                                   float* __restrict__ o) {
    const int tid = threadIdx.x;
    const int wave = tid >> 6;
    const int lane = tid & 63;
    const int l16 = lane & 15;
    const int quad = lane >> 4;
    const int nb = blockIdx.x * 64;
    const int h = blockIdx.y, b = blockIdx.z;

    __shared__ __bf16 p_lds[4][16][72];

    const __bf16* qptr = qkb + ((size_t)b * NPIX + nb + wave * 16 + l16) * 512 + h * 64 + quad * 8;
    bf16x8 a_q = *(const bf16x8*)qptr;

    const __bf16* kbase = qkb + (size_t)b * NPIX * 512 + h * 64 + 32 + quad * 8;
    const __bf16* vbase = Vb + ((size_t)b * NCH + h * HD) * NPIX;

    f32x4 o_acc0 = {0.f, 0.f, 0.f, 0.f}, o_acc1 = {0.f, 0.f, 0.f, 0.f};
    float m_run[4], l_run[4];
#pragma unroll
    for (int r = 0; r < 4; ++r) { m_run[r] = -1e30f; l_run[r] = 0.f; }

    const float scale = 0.17677669529663689f;  // hd^-0.5

    for (int mc = 0; mc < NPIX; mc += 64) {
        f32x4 s[4];
#pragma unroll
        for (int kb = 0; kb < 4; ++kb) {
            bf16x8 b_k = *(const bf16x8*)(kbase + (size_t)(mc + kb * 16 + l16) * 512);
            f32x4 z = {0.f, 0.f, 0.f, 0.f};
            s[kb] = __builtin_amdgcn_mfma_f32_16x16x32_bf16(a_q, b_k, z, 0, 0, 0);
            s[kb] *= scale;
        }
#pragma unroll
        for (int r = 0; r < 4; ++r) {
            float m0 = fmaxf(fmaxf(s[0][r], s[1][r]), fmaxf(s[2][r], s[3][r]));
#pragma unroll
            for (int off = 1; off < 16; off <<= 1) m0 = fmaxf(m0, __shfl_xor(m0, off));
            float mnew = fmaxf(m_run[r], m0);
            float alpha = __expf(m_run[r] - mnew);
            m_run[r] = mnew;
            float ps = 0.f;
#pragma unroll
            for (int kb = 0; kb < 4; ++kb) {
                float pv = __expf(s[kb][r] - mnew);
                p_lds[wave][quad * 4 + r][kb * 16 + l16] = (__bf16)pv;
                ps += pv;
            }
#pragma unroll
            for (int off = 1; off < 16; off <<= 1) ps += __shfl_xor(ps, off);
            l_run[r] = l_run[r] * alpha + ps;
            o_acc0[r] *= alpha;
            o_acc1[r] *= alpha;
        }
#pragma unroll
        for (int kh = 0; kh < 2; ++kh) {
            bf16x8 a_p = *(const bf16x8*)&p_lds[wave][l16][kh * 32 + quad * 8];
            const __bf16* vp0 = vbase + (size_t)l16 * NPIX + mc + kh * 32 + quad * 8;
            bf16x8 b_v0 = *(const bf16x8*)vp0;
            bf16x8 b_v1 = *(const bf16x8*)(vp0 + (size_t)16 * NPIX);
            o_acc0 = __builtin_amdgcn_mfma_f32_16x16x32_bf16(a_p, b_v0, o_acc0, 0, 0, 0);
            o_acc1 = __builtin_amdgcn_mfma_f32_16x16x32_bf16(a_p, b_v1, o_acc1, 0, 0, 0);
        }
    }

    const int qrow = nb + wave * 16 + quad * 4;
#pragma unroll
    for (int r = 0; r < 4; ++r) {
        float inv = 1.f / l_run[r];
        o[((size_t)b * NCH + h * HD + l16) * NPIX + qrow + r]      = o_acc0[r] * inv;
        o[((size_t)b * NCH + h * HD + 16 + l16) * NPIX + qrow + r] = o_acc1[r] * inv;
    }
}

extern "C" void kernel_launch(void* const* d_in, const int* in_sizes, int n_in,
                              void* d_out, int out_size, void* d_ws, size_t ws_size,
                              hipStream_t stream) {
    const float* x    = (const float*)d_in[0];
    const float* qk_w = (const float*)d_in[1];
    const float* qk_b = (const float*)d_in[2];
    const float* v_w  = (const float*)d_in[3];
    const float* v_b  = (const float*)d_in[4];
    const float* pe_w = (const float*)d_in[5];
    const float* pe_b = (const float*)d_in[6];
    const float* pj_w = (const float*)d_in[7];
    const float* pj_b = (const float*)d_in[8];
    const float* f1_w = (const float*)d_in[9];
    const float* f1_b = (const float*)d_in[10];
    const float* f2_w = (const float*)d_in[11];
    const float* f2_b = (const float*)d_in[12];
    float* out = (float*)d_out;

    const int B = 2;
    const size_t plane = (size_t)NCH * NPIX;       // 589824
    const size_t bp = (size_t)B * plane;           // 1179648

    float* v_bu  = (float*)d_ws;                   // NCHW f32
    float* pe_bu = v_bu + bp;
    float* o_bu  = pe_bu + bp;
    float* x1_f  = o_bu + bp;
    __bf16* Xb   = (__bf16*)(x1_f + bp);           // NHWC bf16 [b][n][256]
    __bf16* qkb  = Xb + bp;                        // NHWC bf16 [b][n][512]
    __bf16* Vb   = qkb + 2 * bp;                   // NCHW bf16 (= [bh][d][n])
    __bf16* opb  = Vb + bp;                        // NHWC bf16 (o+pe)
    __bf16* x1b  = opb + bp;                       // NHWC bf16
    __bf16* hb   = x1b + bp;                       // NHWC bf16 [b][n][512]
    __bf16* Wall = hb + 2 * bp;                    // 524288 bf16
    __bf16* Wq = Wall;
    __bf16* Wv = Wall + 131072;
    __bf16* Wp = Wall + 196608;
    __bf16* W1 = Wall + 262144;
    __bf16* W2 = Wall + 393216;

    wcast_k<<<512, 256, 0, stream>>>(qk_w, v_w, pj_w, f1_w, f2_w, Wall);
    nchw2nhwc_k<false><<<dim3(NPIX / 64, 4, B), 256, 0, stream>>>(x, nullptr, Xb);
    // qk = conv1x1(x) -> NHWC bf16
    convmm_k<256, 512, 0><<<dim3(NPIX / 64, 8, B), 256, 0, stream>>>(
        Xb, Wq, qk_b, nullptr, nullptr, qkb);
    // v_full -> NCHW f32 (dwconv) + NCHW bf16 (attention V^T)
    convmm_k<256, 256, 1><<<dim3(NPIX / 64, 4, B), 256, 0, stream>>>(
        Xb, Wv, v_b, nullptr, v_bu, Vb);
    // pe = dwconv7x7(v_full) + pe_b
    dwconv_k<<<dim3(NCH, B), 256, 0, stream>>>(v_bu, pe_w, pe_b, pe_bu);
    // o = attention(q, k, v)
    attn_mfma_k<<<dim3(NPIX / 64, NHD, B), 256, 0, stream>>>(qkb, Vb, o_bu);
    // (o + pe) -> NHWC bf16
    nchw2nhwc_k<true><<<dim3(NPIX / 64, 4, B), 256, 0, stream>>>(o_bu, pe_bu, opb);
    // x1 = x + proj(o+pe): NCHW f32 + NHWC bf16
    convmm_k<256, 256, 2><<<dim3(NPIX / 64, 4, B), 256, 0, stream>>>(
        opb, Wp, pj_b, x, x1_f, x1b);
    // h = silu(fc1(x1)) -> NHWC bf16
    convmm_k<256, 512, 3><<<dim3(NPIX / 64, 8, B), 256, 0, stream>>>(
        x1b, W1, f1_b, nullptr, nullptr, hb);
    // out = x1 + fc2(h) -> NCHW f32
    convmm_k<512, 256, 4><<<dim3(NPIX / 64, 4, B), 256, 0, stream>>>(
        hb, W2, f2_b, x1_f, out, nullptr);
}

// Round 5
// 251.576 us; speedup vs baseline: 4.2901x; 1.1582x over previous
//
#include <hip/hip_runtime.h>
#include <hip/hip_bf16.h>

#define NCH 256      // C
#define NHD 8        // heads
#define HD 32        // head dim
#define NPIX 2304    // 48*48
#define H1DIM 512

typedef __attribute__((ext_vector_type(8))) __bf16 bf16x8;
typedef __attribute__((ext_vector_type(4))) float f32x4;

// ---------------- weight cast f32 -> bf16 (all 5 matrices, one launch) -------
__global__ __launch_bounds__(256) void wcast_k(
    const float* __restrict__ w0, const float* __restrict__ w1,
    const float* __restrict__ w2, const float* __restrict__ w3,
    const float* __restrict__ w4, __bf16* __restrict__ dst) {
    int i = blockIdx.x * 256 + threadIdx.x;
    const float* src; int off;
    if (i < 32768)      { src = w0; off = i; }
    else if (i < 49152) { src = w1; off = i - 32768; }
    else if (i < 65536) { src = w2; off = i - 49152; }
    else if (i < 98304) { src = w3; off = i - 65536; }
    else                { src = w4; off = i - 98304; }
    float4 v = ((const float4*)src)[off];
    union { __bf16 h[4]; uint2 u; } pk;
    pk.h[0] = (__bf16)v.x; pk.h[1] = (__bf16)v.y;
    pk.h[2] = (__bf16)v.z; pk.h[3] = (__bf16)v.w;
    ((uint2*)dst)[i] = pk.u;
}

// ---------------- NCHW f32 (+optional add) -> NHWC bf16 transpose ------------
template <bool ADD>
__global__ __launch_bounds__(256) void nchw2nhwc_k(const float* __restrict__ s1,
                                                   const float* __restrict__ s2,
                                                   __bf16* __restrict__ dst) {
    const int tid = threadIdx.x;
    const int n0 = blockIdx.x * 64;
    const int c0 = blockIdx.y * 64;
    const int b = blockIdx.z;
    __shared__ float tile[64][65];
    const size_t sb = ((size_t)b * NCH + c0) * NPIX + n0;
#pragma unroll
    for (int i = 0; i < 16; ++i) {
        int idx = tid + i * 256;
        int r = idx >> 6, c = idx & 63;
        float v = s1[sb + (size_t)r * NPIX + c];
        if constexpr (ADD) v += s2[sb + (size_t)r * NPIX + c];
        tile[r][c] = v;
    }
    __syncthreads();
#pragma unroll
    for (int i = 0; i < 8; ++i) {
        int idx = tid + i * 256;
        int nn = idx >> 5, cp = (idx & 31) * 2;
        union { __bf16 h[2]; unsigned u; } pk;
        pk.h[0] = (__bf16)tile[cp][nn];
        pk.h[1] = (__bf16)tile[cp + 1][nn];
        *(unsigned*)&dst[((size_t)b * NPIX + n0 + nn) * NCH + c0 + cp] = pk.u;
    }
}

// ---------------- MFMA 1x1 conv ----------------
// MODE 0: qk   -> out_b NHWC bf16
// MODE 1: v    -> out_f NCHW f32
// MODE 2: proj -> +resid(NCHW); out_f NCHW f32 + out_b NHWC bf16
// MODE 3: fc1  -> silu; out_b NHWC bf16
// MODE 4: fc2  -> +resid(NCHW); out_f NCHW f32
template <int IC, int OC, int MODE>
__global__ __launch_bounds__(256) void convmm_k(
    const __bf16* __restrict__ A, const __bf16* __restrict__ W,
    const float* __restrict__ bias, const float* __restrict__ resid,
    float* __restrict__ out_f, __bf16* __restrict__ out_b) {
    const int tid = threadIdx.x;
    const int wave = tid >> 6, lane = tid & 63;
    const int l16 = lane & 15, quad = lane >> 4;
    const int m0 = blockIdx.x * 64 + wave * 16;
    const int oc0 = blockIdx.y * 64;
    const int b = blockIdx.z;

    const __bf16* aptr = A + ((size_t)b * NPIX + m0 + l16) * IC + quad * 8;
    const __bf16* bptr = W + ((size_t)(oc0 + l16)) * IC + quad * 8;

    f32x4 acc[4] = {{0.f,0.f,0.f,0.f},{0.f,0.f,0.f,0.f},{0.f,0.f,0.f,0.f},{0.f,0.f,0.f,0.f}};
#pragma unroll 8
    for (int k = 0; k < IC; k += 32) {
        bf16x8 af = *(const bf16x8*)(aptr + k);
#pragma unroll
        for (int t = 0; t < 4; ++t) {
            bf16x8 bf = *(const bf16x8*)(bptr + (size_t)t * 16 * IC + k);
            acc[t] = __builtin_amdgcn_mfma_f32_16x16x32_bf16(af, bf, acc[t], 0, 0, 0);
        }
    }

    const int mb = m0 + quad * 4;
#pragma unroll
    for (int t = 0; t < 4; ++t) {
        const int oc = oc0 + t * 16 + l16;
        const float bb = bias[oc];
        if constexpr (MODE == 0 || MODE == 3) {
#pragma unroll
            for (int r = 0; r < 4; ++r) {
                float v = acc[t][r] + bb;
                if constexpr (MODE == 3) v = v / (1.f + __expf(-v));
                out_b[((size_t)b * NPIX + mb + r) * OC + oc] = (__bf16)v;
            }
        } else if constexpr (MODE == 1) {
            const size_t base = ((size_t)b * OC + oc) * NPIX + mb;
            float4 vf; float* vp = &vf.x;
#pragma unroll
            for (int r = 0; r < 4; ++r) vp[r] = acc[t][r] + bb;
            *(float4*)&out_f[base] = vf;
        } else if constexpr (MODE == 2) {
            const size_t base = ((size_t)b * OC + oc) * NPIX + mb;
            float4 xr = *(const float4*)&resid[base];
            const float* xp = &xr.x;
            float4 vf; float* vp = &vf.x;
#pragma unroll
            for (int r = 0; r < 4; ++r) {
                float v = acc[t][r] + bb + xp[r];
                vp[r] = v;
                out_b[((size_t)b * NPIX + mb + r) * OC + oc] = (__bf16)v;
            }
            *(float4*)&out_f[base] = vf;
        } else {  // MODE 4
            const size_t base = ((size_t)b * OC + oc) * NPIX + mb;
            float4 xr = *(const float4*)&resid[base];
            const float* xp = &xr.x;
            float4 vf; float* vp = &vf.x;
#pragma unroll
            for (int r = 0; r < 4; ++r) vp[r] = acc[t][r] + bb + xp[r];
            *(float4*)&out_f[base] = vf;
        }
    }
}

// ---------------- depthwise 7x7, SAME, per (b,c) plane ----------------
__global__ __launch_bounds__(256) void dwconv_k(const float* __restrict__ vb,
                                                const float* __restrict__ pw,
                                                const float* __restrict__ pb,
                                                float* __restrict__ pe) {
    const int c = blockIdx.x, b = blockIdx.y, tid = threadIdx.x;
    __shared__ float plane[NPIX];
    __shared__ float wk[49];
    const size_t base = ((size_t)b * NCH + c) * NPIX;
    for (int i = tid; i < NPIX; i += 256) plane[i] = vb[base + i];
    if (tid < 49) wk[tid] = pw[c * 49 + tid];
    float bb = pb[c];
    __syncthreads();
    for (int p = tid; p < NPIX; p += 256) {
        int y = p / 48, x = p - y * 48;
        float s = bb;
#pragma unroll
        for (int ky = 0; ky < 7; ++ky) {
            int yy = y + ky - 3;
            if ((unsigned)yy < 48u) {
#pragma unroll
                for (int kx = 0; kx < 7; ++kx) {
                    int xx = x + kx - 3;
                    if ((unsigned)xx < 48u) s += wk[ky * 7 + kx] * plane[yy * 48 + xx];
                }
            }
        }
        pe[base + p] = s;
    }
}

// ---------------- repack qk -> Qb (scaled, [bh][n][32]) + Kf (frag-swizzled) --
// Kf fragment for 16-key block kb16: element(lane=(quad,l16), j) = K[kb16*16+l16][quad*8+j]
// grid (NPIX/16, NH, B), block 64
__global__ __launch_bounds__(64) void repack_qk_k(const __bf16* __restrict__ qkb,
                                                  __bf16* __restrict__ Qb,
                                                  __bf16* __restrict__ Kf) {
    const int lane = threadIdx.x;
    const int quad = lane >> 4, l16 = lane & 15;
    const int nb = blockIdx.x * 16;
    const int h = blockIdx.y, b = blockIdx.z;
    const int bh = b * NHD + h;
    const __bf16* src = qkb + ((size_t)(b * NPIX + nb + l16)) * 512 + h * 64 + quad * 8;
    bf16x8 qv = *(const bf16x8*)src;
    bf16x8 kv = *(const bf16x8*)(src + 32);
    const float scale = 0.17677669529663689f;
#pragma unroll
    for (int j = 0; j < 8; ++j) qv[j] = (__bf16)((float)qv[j] * scale);
    *(bf16x8*)(Qb + ((size_t)bh * NPIX + nb + l16) * 32 + quad * 8) = qv;
    *(bf16x8*)(Kf + ((size_t)(bh * 144 + blockIdx.x) * 64 + lane) * 8) = kv;
}

// ---------------- repack v -> Vf (frag-swizzled) ------------------------------
// Vf frag for 32-key block blk, half: element(lane=(quad,l16), j) = V[half*16+l16][blk*32+quad*8+j]
// grid (NPIX/32, NH, B), block 64
__global__ __launch_bounds__(64) void repack_v_k(const float* __restrict__ vb,
                                                 __bf16* __restrict__ Vf) {
    const int lane = threadIdx.x;
    const int quad = lane >> 4, l16 = lane & 15;
    const int blk = blockIdx.x;
    const int h = blockIdx.y, b = blockIdx.z;
    const int bh = b * NHD + h;
#pragma unroll
    for (int half = 0; half < 2; ++half) {
        const float* src = vb + ((size_t)(b * NCH + h * HD + half * 16 + l16)) * NPIX + blk * 32 + quad * 8;
        float4 a = *(const float4*)src;
        float4 c = *(const float4*)(src + 4);
        bf16x8 o;
        o[0] = (__bf16)a.x; o[1] = (__bf16)a.y; o[2] = (__bf16)a.z; o[3] = (__bf16)a.w;
        o[4] = (__bf16)c.x; o[5] = (__bf16)c.y; o[6] = (__bf16)c.z; o[7] = (__bf16)c.w;
        *(bf16x8*)(Vf + (((size_t)(bh * 72 + blk) * 2 + half) * 64 + lane) * 8) = o;
    }
}

// ---------------- MFMA flash attention v2 ----------------
// 4 independent waves x 16 queries; 128-key chunks; key-split 2.
// grid (NPIX/64, NH, B*2); z: b = z>>1, ks = z&1; keys [ks*1152, ks*1152+1152)
// opart: [ks][bh][32][NPIX] f32 (unnormalized); ml: [ks][bh][2][NPIX] f32
__global__ __launch_bounds__(256) void attn_mfma2_k(const __bf16* __restrict__ Qb,
                                                    const __bf16* __restrict__ Kf,
                                                    const __bf16* __restrict__ Vf,
                                                    float* __restrict__ opart,
                                                    float* __restrict__ ml) {
    const int tid = threadIdx.x;
    const int wave = tid >> 6, lane = tid & 63;
    const int l16 = lane & 15, quad = lane >> 4;
    const int nb = blockIdx.x * 64;
    const int h = blockIdx.y;
    const int b = blockIdx.z >> 1, ks = blockIdx.z & 1;
    const int bh = b * NHD + h;

    __shared__ __bf16 p_lds[4][16][136];   // row stride 272B = 17*16 (16B-aligned)

    bf16x8 a_q = *(const bf16x8*)(Qb + ((size_t)bh * NPIX + nb + wave * 16 + l16) * 32 + quad * 8);

    const __bf16* kf = Kf + ((size_t)(bh * 144 + ks * 72) * 64) * 8;
    const __bf16* vf = Vf + ((size_t)(bh * 72 + ks * 36) * 2 * 64) * 8;

    f32x4 o_acc0 = {0.f, 0.f, 0.f, 0.f}, o_acc1 = {0.f, 0.f, 0.f, 0.f};
    float m_run[4], l_part[4];
#pragma unroll
    for (int r = 0; r < 4; ++r) { m_run[r] = -1e30f; l_part[r] = 0.f; }

    for (int it = 0; it < 9; ++it) {
        f32x4 s[8];
#pragma unroll
        for (int kb = 0; kb < 8; ++kb) {
            bf16x8 b_k = *(const bf16x8*)(kf + ((size_t)((it * 8 + kb) * 64 + lane)) * 8);
            f32x4 z = {0.f, 0.f, 0.f, 0.f};
            s[kb] = __builtin_amdgcn_mfma_f32_16x16x32_bf16(a_q, b_k, z, 0, 0, 0);
        }
#pragma unroll
        for (int r = 0; r < 4; ++r) {
            float mx = s[0][r];
#pragma unroll
            for (int kb = 1; kb < 8; ++kb) mx = fmaxf(mx, s[kb][r]);
#pragma unroll
            for (int off = 1; off < 16; off <<= 1) mx = fmaxf(mx, __shfl_xor(mx, off));
            float mnew = fmaxf(m_run[r], mx);
            float alpha = __expf(m_run[r] - mnew);
            m_run[r] = mnew;
            float ps = 0.f;
#pragma unroll
            for (int kb = 0; kb < 8; ++kb) {
                float pv = __expf(s[kb][r] - mnew);
                p_lds[wave][quad * 4 + r][kb * 16 + l16] = (__bf16)pv;
                ps += pv;
            }
            l_part[r] = l_part[r] * alpha + ps;   // per-lane partial; reduced at end
            o_acc0[r] *= alpha;
            o_acc1[r] *= alpha;
        }
#pragma unroll
        for (int kh = 0; kh < 4; ++kh) {
            bf16x8 a_p = *(const bf16x8*)&p_lds[wave][l16][kh * 32 + quad * 8];
            const __bf16* vp = vf + ((size_t)((it * 4 + kh) * 2 * 64 + lane)) * 8;
            bf16x8 b_v0 = *(const bf16x8*)vp;
            bf16x8 b_v1 = *(const bf16x8*)(vp + 64 * 8);
            o_acc0 = __builtin_amdgcn_mfma_f32_16x16x32_bf16(a_p, b_v0, o_acc0, 0, 0, 0);
            o_acc1 = __builtin_amdgcn_mfma_f32_16x16x32_bf16(a_p, b_v1, o_acc1, 0, 0, 0);
        }
    }

    const int qrow = nb + wave * 16 + quad * 4;
    float* op = opart + ((size_t)(ks * 16 + bh) * 32) * NPIX;
    float* mlp = ml + ((size_t)(ks * 16 + bh) * 2) * NPIX;
#pragma unroll
    for (int r = 0; r < 4; ++r) {
        float lr = l_part[r];
#pragma unroll
        for (int off = 1; off < 16; off <<= 1) lr += __shfl_xor(lr, off);
        const int n = qrow + r;
        op[(size_t)l16 * NPIX + n]        = o_acc0[r];
        op[(size_t)(16 + l16) * NPIX + n] = o_acc1[r];
        if (l16 == 0) { mlp[n] = m_run[r]; mlp[NPIX + n] = lr; }
    }
}

// ---------------- merge the 2 key-splits -> o NCHW f32 ----------------
// grid (NPIX/256, B*NH), block 256
__global__ __launch_bounds__(256) void attn_merge_k(const float* __restrict__ opart,
                                                    const float* __restrict__ ml,
                                                    float* __restrict__ o) {
    const int bh = blockIdx.y;
    const int n = blockIdx.x * 256 + threadIdx.x;
    const float m1 = ml[(size_t)(bh * 2) * NPIX + n];
    const float l1 = ml[(size_t)(bh * 2 + 1) * NPIX + n];
    const float m2 = ml[(size_t)((16 + bh) * 2) * NPIX + n];
    const float l2 = ml[(size_t)((16 + bh) * 2 + 1) * NPIX + n];
    const float M = fmaxf(m1, m2);
    const float a1 = __expf(m1 - M), a2 = __expf(m2 - M);
    const float inv = 1.f / (a1 * l1 + a2 * l2);
    const int b = bh >> 3, h = bh & 7;
    const float* o1 = opart + ((size_t)bh * 32) * NPIX + n;
    const float* o2 = opart + ((size_t)(16 + bh) * 32) * NPIX + n;
    float* dst = o + ((size_t)(b * NCH + h * HD)) * NPIX + n;
#pragma unroll 8
    for (int d = 0; d < 32; ++d) {
        dst[(size_t)d * NPIX] = (a1 * o1[(size_t)d * NPIX] + a2 * o2[(size_t)d * NPIX]) * inv;
    }
}

extern "C" void kernel_launch(void* const* d_in, const int* in_sizes, int n_in,
                              void* d_out, int out_size, void* d_ws, size_t ws_size,
                              hipStream_t stream) {
    const float* x    = (const float*)d_in[0];
    const float* qk_w = (const float*)d_in[1];
    const float* qk_b = (const float*)d_in[2];
    const float* v_w  = (const float*)d_in[3];
    const float* v_b  = (const float*)d_in[4];
    const float* pe_w = (const float*)d_in[5];
    const float* pe_b = (const float*)d_in[6];
    const float* pj_w = (const float*)d_in[7];
    const float* pj_b = (const float*)d_in[8];
    const float* f1_w = (const float*)d_in[9];
    const float* f1_b = (const float*)d_in[10];
    const float* f2_w = (const float*)d_in[11];
    const float* f2_b = (const float*)d_in[12];
    float* out = (float*)d_out;

    const int B = 2;
    const size_t plane = (size_t)NCH * NPIX;       // 589824
    const size_t bp = (size_t)B * plane;           // 1179648

    float* v_bu  = (float*)d_ws;                   // NCHW f32
    float* pe_bu = v_bu + bp;
    float* o_bu  = pe_bu + bp;
    float* x1_f  = o_bu + bp;
    float* opart = x1_f + bp;                      // 2*bp f32
    float* mlb   = opart + 2 * bp;                 // 147456 f32
    __bf16* Xb   = (__bf16*)(mlb + 147456);        // NHWC bf16 [b][n][256]
    __bf16* qkb  = Xb + bp;                        // NHWC bf16 [b][n][512]
    __bf16* opb  = qkb + 2 * bp;                   // NHWC bf16 (o+pe)
    __bf16* x1b  = opb + bp;                       // NHWC bf16
    __bf16* hb   = x1b + bp;                       // NHWC bf16 [b][n][512]
    __bf16* Qb   = hb + 2 * bp;                    // [bh][n][32]
    __bf16* Kf   = Qb + bp;                        // frag-swizzled
    __bf16* Vf   = Kf + bp;                        // frag-swizzled
    __bf16* Wall = Vf + bp;                        // 524288 bf16
    __bf16* Wq = Wall;
    __bf16* Wv = Wall + 131072;
    __bf16* Wp = Wall + 196608;
    __bf16* W1 = Wall + 262144;
    __bf16* W2 = Wall + 393216;

    wcast_k<<<512, 256, 0, stream>>>(qk_w, v_w, pj_w, f1_w, f2_w, Wall);
    nchw2nhwc_k<false><<<dim3(NPIX / 64, 4, B), 256, 0, stream>>>(x, nullptr, Xb);
    // qk = conv1x1(x) -> NHWC bf16
    convmm_k<256, 512, 0><<<dim3(NPIX / 64, 8, B), 256, 0, stream>>>(
        Xb, Wq, qk_b, nullptr, nullptr, qkb);
    // repack q/k into attention layouts
    repack_qk_k<<<dim3(NPIX / 16, NHD, B), 64, 0, stream>>>(qkb, Qb, Kf);
    // v_full -> NCHW f32
    convmm_k<256, 256, 1><<<dim3(NPIX / 64, 4, B), 256, 0, stream>>>(
        Xb, Wv, v_b, nullptr, v_bu, nullptr);
    // pe = dwconv7x7(v_full) + pe_b
    dwconv_k<<<dim3(NCH, B), 256, 0, stream>>>(v_bu, pe_w, pe_b, pe_bu);
    // v -> frag-swizzled bf16
    repack_v_k<<<dim3(NPIX / 32, NHD, B), 64, 0, stream>>>(v_bu, Vf);
    // attention partials + merge
    attn_mfma2_k<<<dim3(NPIX / 64, NHD, B * 2), 256, 0, stream>>>(Qb, Kf, Vf, opart, mlb);
    attn_merge_k<<<dim3(NPIX / 256, B * NHD), 256, 0, stream>>>(opart, mlb, o_bu);
    // (o + pe) -> NHWC bf16
    nchw2nhwc_k<true><<<dim3(NPIX / 64, 4, B), 256, 0, stream>>>(o_bu, pe_bu, opb);
    // x1 = x + proj(o+pe): NCHW f32 + NHWC bf16
    convmm_k<256, 256, 2><<<dim3(NPIX / 64, 4, B), 256, 0, stream>>>(
        opb, Wp, pj_b, x, x1_f, x1b);
    // h = silu(fc1(x1)) -> NHWC bf16
    convmm_k<256, 512, 3><<<dim3(NPIX / 64, 8, B), 256, 0, stream>>>(
        x1b, W1, f1_b, nullptr, nullptr, hb);
    // out = x1 + fc2(h) -> NCHW f32
    convmm_k<512, 256, 4><<<dim3(NPIX / 64, 4, B), 256, 0, stream>>>(
        hb, W2, f2_b, x1_f, out, nullptr);
}

// Round 6
// 248.047 us; speedup vs baseline: 4.3511x; 1.0142x over previous
//
#include <hip/hip_runtime.h>
#include <hip/hip_bf16.h>

#define NCH 256      // C
#define NHD 8        // heads
#define HD 32        // head dim
#define NPIX 2304    // 48*48
#define H1DIM 512

typedef __attribute__((ext_vector_type(8))) __bf16 bf16x8;
typedef __attribute__((ext_vector_type(4))) float f32x4;

// ---------------- weight cast f32 -> bf16 (all 5 matrices, one launch) -------
__global__ __launch_bounds__(256) void wcast_k(
    const float* __restrict__ w0, const float* __restrict__ w1,
    const float* __restrict__ w2, const float* __restrict__ w3,
    const float* __restrict__ w4, __bf16* __restrict__ dst) {
    int i = blockIdx.x * 256 + threadIdx.x;
    const float* src; int off;
    if (i < 32768)      { src = w0; off = i; }
    else if (i < 49152) { src = w1; off = i - 32768; }
    else if (i < 65536) { src = w2; off = i - 49152; }
    else if (i < 98304) { src = w3; off = i - 65536; }
    else                { src = w4; off = i - 98304; }
    float4 v = ((const float4*)src)[off];
    union { __bf16 h[4]; uint2 u; } pk;
    pk.h[0] = (__bf16)v.x; pk.h[1] = (__bf16)v.y;
    pk.h[2] = (__bf16)v.z; pk.h[3] = (__bf16)v.w;
    ((uint2*)dst)[i] = pk.u;
}

// ---------------- NCHW f32 (+optional add) -> NHWC bf16 transpose ------------
template <bool ADD>
__global__ __launch_bounds__(256) void nchw2nhwc_k(const float* __restrict__ s1,
                                                   const float* __restrict__ s2,
                                                   __bf16* __restrict__ dst) {
    const int tid = threadIdx.x;
    const int n0 = blockIdx.x * 64;
    const int c0 = blockIdx.y * 64;
    const int b = blockIdx.z;
    __shared__ float tile[64][65];
    const size_t sb = ((size_t)b * NCH + c0) * NPIX + n0;
#pragma unroll
    for (int i = 0; i < 16; ++i) {
        int idx = tid + i * 256;
        int r = idx >> 6, c = idx & 63;
        float v = s1[sb + (size_t)r * NPIX + c];
        if constexpr (ADD) v += s2[sb + (size_t)r * NPIX + c];
        tile[r][c] = v;
    }
    __syncthreads();
#pragma unroll
    for (int i = 0; i < 8; ++i) {
        int idx = tid + i * 256;
        int nn = idx >> 5, cp = (idx & 31) * 2;
        union { __bf16 h[2]; unsigned u; } pk;
        pk.h[0] = (__bf16)tile[cp][nn];
        pk.h[1] = (__bf16)tile[cp + 1][nn];
        *(unsigned*)&dst[((size_t)b * NPIX + n0 + nn) * NCH + c0 + cp] = pk.u;
    }
}

// ---------------- MFMA 1x1 conv ----------------
// MODE 0: qk   -> out_b NHWC bf16
// MODE 1: v    -> out_f NCHW f32
// MODE 2: proj -> +resid(NCHW); out_f NCHW f32 + out_b NHWC bf16
// MODE 3: fc1  -> silu; out_b NHWC bf16
// MODE 4: fc2  -> +resid(NCHW); out_f NCHW f32
template <int IC, int OC, int MODE>
__global__ __launch_bounds__(256) void convmm_k(
    const __bf16* __restrict__ A, const __bf16* __restrict__ W,
    const float* __restrict__ bias, const float* __restrict__ resid,
    float* __restrict__ out_f, __bf16* __restrict__ out_b) {
    const int tid = threadIdx.x;
    const int wave = tid >> 6, lane = tid & 63;
    const int l16 = lane & 15, quad = lane >> 4;
    const int m0 = blockIdx.x * 64 + wave * 16;
    const int oc0 = blockIdx.y * 64;
    const int b = blockIdx.z;

    const __bf16* aptr = A + ((size_t)b * NPIX + m0 + l16) * IC + quad * 8;
    const __bf16* bptr = W + ((size_t)(oc0 + l16)) * IC + quad * 8;

    f32x4 acc[4] = {{0.f,0.f,0.f,0.f},{0.f,0.f,0.f,0.f},{0.f,0.f,0.f,0.f},{0.f,0.f,0.f,0.f}};
#pragma unroll 8
    for (int k = 0; k < IC; k += 32) {
        bf16x8 af = *(const bf16x8*)(aptr + k);
#pragma unroll
        for (int t = 0; t < 4; ++t) {
            bf16x8 bf = *(const bf16x8*)(bptr + (size_t)t * 16 * IC + k);
            acc[t] = __builtin_amdgcn_mfma_f32_16x16x32_bf16(af, bf, acc[t], 0, 0, 0);
        }
    }

    const int mb = m0 + quad * 4;
#pragma unroll
    for (int t = 0; t < 4; ++t) {
        const int oc = oc0 + t * 16 + l16;
        const float bb = bias[oc];
        if constexpr (MODE == 0 || MODE == 3) {
#pragma unroll
            for (int r = 0; r < 4; ++r) {
                float v = acc[t][r] + bb;
                if constexpr (MODE == 3) v = v / (1.f + __expf(-v));
                out_b[((size_t)b * NPIX + mb + r) * OC + oc] = (__bf16)v;
            }
        } else if constexpr (MODE == 1) {
            const size_t base = ((size_t)b * OC + oc) * NPIX + mb;
            float4 vf; float* vp = &vf.x;
#pragma unroll
            for (int r = 0; r < 4; ++r) vp[r] = acc[t][r] + bb;
            *(float4*)&out_f[base] = vf;
        } else if constexpr (MODE == 2) {
            const size_t base = ((size_t)b * OC + oc) * NPIX + mb;
            float4 xr = *(const float4*)&resid[base];
            const float* xp = &xr.x;
            float4 vf; float* vp = &vf.x;
#pragma unroll
            for (int r = 0; r < 4; ++r) {
                float v = acc[t][r] + bb + xp[r];
                vp[r] = v;
                out_b[((size_t)b * NPIX + mb + r) * OC + oc] = (__bf16)v;
            }
            *(float4*)&out_f[base] = vf;
        } else {  // MODE 4
            const size_t base = ((size_t)b * OC + oc) * NPIX + mb;
            float4 xr = *(const float4*)&resid[base];
            const float* xp = &xr.x;
            float4 vf; float* vp = &vf.x;
#pragma unroll
            for (int r = 0; r < 4; ++r) vp[r] = acc[t][r] + bb + xp[r];
            *(float4*)&out_f[base] = vf;
        }
    }
}

// ---------------- depthwise 7x7, SAME, per (b,c) plane ----------------
__global__ __launch_bounds__(256) void dwconv_k(const float* __restrict__ vb,
                                                const float* __restrict__ pw,
                                                const float* __restrict__ pb,
                                                float* __restrict__ pe) {
    const int c = blockIdx.x, b = blockIdx.y, tid = threadIdx.x;
    __shared__ float plane[NPIX];
    __shared__ float wk[49];
    const size_t base = ((size_t)b * NCH + c) * NPIX;
    for (int i = tid; i < NPIX; i += 256) plane[i] = vb[base + i];
    if (tid < 49) wk[tid] = pw[c * 49 + tid];
    float bb = pb[c];
    __syncthreads();
    for (int p = tid; p < NPIX; p += 256) {
        int y = p / 48, x = p - y * 48;
        float s = bb;
#pragma unroll
        for (int ky = 0; ky < 7; ++ky) {
            int yy = y + ky - 3;
            if ((unsigned)yy < 48u) {
#pragma unroll
                for (int kx = 0; kx < 7; ++kx) {
                    int xx = x + kx - 3;
                    if ((unsigned)xx < 48u) s += wk[ky * 7 + kx] * plane[yy * 48 + xx];
                }
            }
        }
        pe[base + p] = s;
    }
}

// ---------------- repack qk -> Qb (scaled, [bh][n][32]) + Kf (frag-swizzled) --
// Q scale folds hd^-0.5 AND log2(e) (softmax uses exp2).
// grid (NPIX/16, NH, B), block 64
__global__ __launch_bounds__(64) void repack_qk_k(const __bf16* __restrict__ qkb,
                                                  __bf16* __restrict__ Qb,
                                                  __bf16* __restrict__ Kf) {
    const int lane = threadIdx.x;
    const int quad = lane >> 4, l16 = lane & 15;
    const int nb = blockIdx.x * 16;
    const int h = blockIdx.y, b = blockIdx.z;
    const int bh = b * NHD + h;
    const __bf16* src = qkb + ((size_t)(b * NPIX + nb + l16)) * 512 + h * 64 + quad * 8;
    bf16x8 qv = *(const bf16x8*)src;
    bf16x8 kv = *(const bf16x8*)(src + 32);
    const float scale = 0.17677669529663689f * 1.4426950408889634f;  // hd^-0.5 * log2e
#pragma unroll
    for (int j = 0; j < 8; ++j) qv[j] = (__bf16)((float)qv[j] * scale);
    *(bf16x8*)(Qb + ((size_t)bh * NPIX + nb + l16) * 32 + quad * 8) = qv;
    *(bf16x8*)(Kf + ((size_t)(bh * 144 + blockIdx.x) * 64 + lane) * 8) = kv;
}

// ---------------- repack v -> Vf (A-frag for PV, 16-key tiles) ---------------
// tile t: lane (l16,quad) holds [ V[l16][16t+4q+j] j<4 | V[16+l16][16t+4q+j] j<4 ]
// grid (NPIX/16, NH, B), block 64
__global__ __launch_bounds__(64) void repack_v_k(const float* __restrict__ vb,
                                                 __bf16* __restrict__ Vf) {
    const int lane = threadIdx.x;
    const int quad = lane >> 4, l16 = lane & 15;
    const int t = blockIdx.x;
    const int h = blockIdx.y, b = blockIdx.z;
    const int bh = b * NHD + h;
    const float* s0 = vb + ((size_t)(b * NCH + h * HD + l16)) * NPIX + t * 16 + quad * 4;
    float4 a = *(const float4*)s0;
    float4 c = *(const float4*)(s0 + (size_t)16 * NPIX);
    bf16x8 o;
    o[0] = (__bf16)a.x; o[1] = (__bf16)a.y; o[2] = (__bf16)a.z; o[3] = (__bf16)a.w;
    o[4] = (__bf16)c.x; o[5] = (__bf16)c.y; o[6] = (__bf16)c.z; o[7] = (__bf16)c.w;
    *(bf16x8*)(Vf + ((size_t)(bh * 144 + t) * 64 + lane) * 8) = o;
}

// ---------------- MFMA flash attention v3 ----------------
// S^T = K·Q^T (C layout: col=q, row=key) -> exp2 -> feed directly as PV B-frag
// (upper 4 B elements zero; A upper half don't-care). No LDS, no barriers,
// no running max (scores |s|<~1 by construction; softmax shift-invariant).
// grid (NPIX/64, NH, B*2): z -> b=z>>1, ks=z&1 (keys [ks*1152, +1152))
// opart: [ks*16+bh][32][NPIX] f32 unnormalized; lpart: [ks*16+bh][NPIX] f32
__global__ __launch_bounds__(256) void attn_mfma3_k(const __bf16* __restrict__ Qb,
                                                    const __bf16* __restrict__ Kf,
                                                    const __bf16* __restrict__ Vf,
                                                    float* __restrict__ opart,
                                                    float* __restrict__ lpart) {
    const int tid = threadIdx.x;
    const int wave = tid >> 6, lane = tid & 63;
    const int l16 = lane & 15, quad = lane >> 4;
    const int nb = blockIdx.x * 64;
    const int h = blockIdx.y;
    const int b = blockIdx.z >> 1, ks = blockIdx.z & 1;
    const int bh = b * NHD + h;

    // Q as B-frag: lane l16 = query, quad*8+j = d
    bf16x8 b_q = *(const bf16x8*)(Qb + ((size_t)bh * NPIX + nb + wave * 16 + l16) * 32 + quad * 8);

    const __bf16* kf = Kf + ((size_t)(bh * 144 + ks * 72) * 64 + lane) * 8;
    const __bf16* vf = Vf + ((size_t)(bh * 144 + ks * 72) * 64 + lane) * 8;

    f32x4 o_acc0 = {0.f, 0.f, 0.f, 0.f}, o_acc1 = {0.f, 0.f, 0.f, 0.f};
    f32x4 l_acc = {0.f, 0.f, 0.f, 0.f};

#pragma unroll 4
    for (int t = 0; t < 72; ++t) {
        // K A-frag: lane l16 = key (16t+l16), quad*8+j = d
        bf16x8 a_k = *(const bf16x8*)(kf + (size_t)t * 512);
        f32x4 z = {0.f, 0.f, 0.f, 0.f};
        f32x4 s = __builtin_amdgcn_mfma_f32_16x16x32_bf16(a_k, b_q, z, 0, 0, 0);
        // p = exp2(s) ; s reg r <-> key 16t+quad*4+r, col q=l16
        f32x4 p;
#pragma unroll
        for (int r = 0; r < 4; ++r) p[r] = __builtin_amdgcn_exp2f(s[r]);
        l_acc += p;
        // PV B-frag: j<4 = p (hw k = quad*8+j pairs with V at same (quad,j)), j>=4 = 0
        bf16x8 bfrag = {};
        bfrag[0] = (__bf16)p[0]; bfrag[1] = (__bf16)p[1];
        bfrag[2] = (__bf16)p[2]; bfrag[3] = (__bf16)p[3];
        // V A-frags: lo half = d 0..15, hi half = d 16..31 (upper j>=4 don't-care)
        bf16x8 va = *(const bf16x8*)(vf + (size_t)t * 512);
        bf16x8 va1;
        va1[0] = va[4]; va1[1] = va[5]; va1[2] = va[6]; va1[3] = va[7];
        va1[4] = va[0]; va1[5] = va[1]; va1[6] = va[2]; va1[7] = va[3];
        o_acc0 = __builtin_amdgcn_mfma_f32_16x16x32_bf16(va,  bfrag, o_acc0, 0, 0, 0);
        o_acc1 = __builtin_amdgcn_mfma_f32_16x16x32_bf16(va1, bfrag, o_acc1, 0, 0, 0);
    }

    // l[q] = sum over regs + cross-quad
    float lsum = l_acc[0] + l_acc[1] + l_acc[2] + l_acc[3];
    lsum += __shfl_xor(lsum, 16);
    lsum += __shfl_xor(lsum, 32);

    const int n = nb + wave * 16 + l16;
    float* op = opart + ((size_t)(ks * 16 + bh) * 32) * NPIX;
#pragma unroll
    for (int r = 0; r < 4; ++r) {
        // O^T C-layout: col=q(l16), row=d=quad*4+r (+16 for half 1)
        op[(size_t)(quad * 4 + r) * NPIX + n]      = o_acc0[r];
        op[(size_t)(16 + quad * 4 + r) * NPIX + n] = o_acc1[r];
    }
    if (quad == 0) lpart[(size_t)(ks * 16 + bh) * NPIX + n] = lsum;
}

// ---------------- merge the 2 key-splits -> o NCHW f32 ----------------
// grid (NPIX/256, B*NH), block 256
__global__ __launch_bounds__(256) void attn_merge_k(const float* __restrict__ opart,
                                                    const float* __restrict__ lpart,
                                                    float* __restrict__ o) {
    const int bh = blockIdx.y;
    const int n = blockIdx.x * 256 + threadIdx.x;
    const float l1 = lpart[(size_t)bh * NPIX + n];
    const float l2 = lpart[(size_t)(16 + bh) * NPIX + n];
    const float inv = 1.f / (l1 + l2);
    const int b = bh >> 3, h = bh & 7;
    const float* o1 = opart + ((size_t)bh * 32) * NPIX + n;
    const float* o2 = opart + ((size_t)(16 + bh) * 32) * NPIX + n;
    float* dst = o + ((size_t)(b * NCH + h * HD)) * NPIX + n;
#pragma unroll 8
    for (int d = 0; d < 32; ++d) {
        dst[(size_t)d * NPIX] = (o1[(size_t)d * NPIX] + o2[(size_t)d * NPIX]) * inv;
    }
}

extern "C" void kernel_launch(void* const* d_in, const int* in_sizes, int n_in,
                              void* d_out, int out_size, void* d_ws, size_t ws_size,
                              hipStream_t stream) {
    const float* x    = (const float*)d_in[0];
    const float* qk_w = (const float*)d_in[1];
    const float* qk_b = (const float*)d_in[2];
    const float* v_w  = (const float*)d_in[3];
    const float* v_b  = (const float*)d_in[4];
    const float* pe_w = (const float*)d_in[5];
    const float* pe_b = (const float*)d_in[6];
    const float* pj_w = (const float*)d_in[7];
    const float* pj_b = (const float*)d_in[8];
    const float* f1_w = (const float*)d_in[9];
    const float* f1_b = (const float*)d_in[10];
    const float* f2_w = (const float*)d_in[11];
    const float* f2_b = (const float*)d_in[12];
    float* out = (float*)d_out;

    const int B = 2;
    const size_t plane = (size_t)NCH * NPIX;       // 589824
    const size_t bp = (size_t)B * plane;           // 1179648

    float* v_bu  = (float*)d_ws;                   // NCHW f32
    float* pe_bu = v_bu + bp;
    float* o_bu  = pe_bu + bp;
    float* x1_f  = o_bu + bp;
    float* opart = x1_f + bp;                      // 2*bp f32
    float* lpart = opart + 2 * bp;                 // 73728 f32
    __bf16* Xb   = (__bf16*)(lpart + 73728);       // NHWC bf16 [b][n][256]
    __bf16* qkb  = Xb + bp;                        // NHWC bf16 [b][n][512]
    __bf16* opb  = qkb + 2 * bp;                   // NHWC bf16 (o+pe)
    __bf16* x1b  = opb + bp;                       // NHWC bf16
    __bf16* hb   = x1b + bp;                       // NHWC bf16 [b][n][512]
    __bf16* Qb   = hb + 2 * bp;                    // [bh][n][32]
    __bf16* Kf   = Qb + bp;                        // frag-swizzled (A-frag tiles)
    __bf16* Vf   = Kf + bp;                        // frag-swizzled (PV A-frag tiles)
    __bf16* Wall = Vf + bp;                        // 524288 bf16
    __bf16* Wq = Wall;
    __bf16* Wv = Wall + 131072;
    __bf16* Wp = Wall + 196608;
    __bf16* W1 = Wall + 262144;
    __bf16* W2 = Wall + 393216;

    wcast_k<<<512, 256, 0, stream>>>(qk_w, v_w, pj_w, f1_w, f2_w, Wall);
    nchw2nhwc_k<false><<<dim3(NPIX / 64, 4, B), 256, 0, stream>>>(x, nullptr, Xb);
    // qk = conv1x1(x) -> NHWC bf16
    convmm_k<256, 512, 0><<<dim3(NPIX / 64, 8, B), 256, 0, stream>>>(
        Xb, Wq, qk_b, nullptr, nullptr, qkb);
    // repack q/k into attention layouts
    repack_qk_k<<<dim3(NPIX / 16, NHD, B), 64, 0, stream>>>(qkb, Qb, Kf);
    // v_full -> NCHW f32
    convmm_k<256, 256, 1><<<dim3(NPIX / 64, 4, B), 256, 0, stream>>>(
        Xb, Wv, v_b, nullptr, v_bu, nullptr);
    // pe = dwconv7x7(v_full) + pe_b
    dwconv_k<<<dim3(NCH, B), 256, 0, stream>>>(v_bu, pe_w, pe_b, pe_bu);
    // v -> PV A-frag tiles
    repack_v_k<<<dim3(NPIX / 16, NHD, B), 64, 0, stream>>>(v_bu, Vf);
    // attention partials + merge
    attn_mfma3_k<<<dim3(NPIX / 64, NHD, B * 2), 256, 0, stream>>>(Qb, Kf, Vf, opart, lpart);
    attn_merge_k<<<dim3(NPIX / 256, B * NHD), 256, 0, stream>>>(opart, lpart, o_bu);
    // (o + pe) -> NHWC bf16
    nchw2nhwc_k<true><<<dim3(NPIX / 64, 4, B), 256, 0, stream>>>(o_bu, pe_bu, opb);
    // x1 = x + proj(o+pe): NCHW f32 + NHWC bf16
    convmm_k<256, 256, 2><<<dim3(NPIX / 64, 4, B), 256, 0, stream>>>(
        opb, Wp, pj_b, x, x1_f, x1b);
    // h = silu(fc1(x1)) -> NHWC bf16
    convmm_k<256, 512, 3><<<dim3(NPIX / 64, 8, B), 256, 0, stream>>>(
        x1b, W1, f1_b, nullptr, nullptr, hb);
    // out = x1 + fc2(h) -> NCHW f32
    convmm_k<512, 256, 4><<<dim3(NPIX / 64, 4, B), 256, 0, stream>>>(
        hb, W2, f2_b, x1_f, out, nullptr);
}

// Round 7
// 219.901 us; speedup vs baseline: 4.9080x; 1.1280x over previous
//
#include <hip/hip_runtime.h>
#include <hip/hip_bf16.h>

#define NCH 256      // C
#define NHD 8        // heads
#define HD 32        // head dim
#define NPIX 2304    // 48*48
#define H1DIM 512

typedef __attribute__((ext_vector_type(8))) __bf16 bf16x8;
typedef __attribute__((ext_vector_type(4))) float f32x4;

// ---------------- weight cast f32 -> bf16 (all 5 matrices, one launch) -------
__global__ __launch_bounds__(256) void wcast_k(
    const float* __restrict__ w0, const float* __restrict__ w1,
    const float* __restrict__ w2, const float* __restrict__ w3,
    const float* __restrict__ w4, __bf16* __restrict__ dst) {
    int i = blockIdx.x * 256 + threadIdx.x;
    const float* src; int off;
    if (i < 32768)      { src = w0; off = i; }
    else if (i < 49152) { src = w1; off = i - 32768; }
    else if (i < 65536) { src = w2; off = i - 49152; }
    else if (i < 98304) { src = w3; off = i - 65536; }
    else                { src = w4; off = i - 98304; }
    float4 v = ((const float4*)src)[off];
    union { __bf16 h[4]; uint2 u; } pk;
    pk.h[0] = (__bf16)v.x; pk.h[1] = (__bf16)v.y;
    pk.h[2] = (__bf16)v.z; pk.h[3] = (__bf16)v.w;
    ((uint2*)dst)[i] = pk.u;
}

// ---------------- NCHW f32 -> NHWC bf16 transpose ----------------------------
__global__ __launch_bounds__(256) void nchw2nhwc_k(const float* __restrict__ s1,
                                                   __bf16* __restrict__ dst) {
    const int tid = threadIdx.x;
    const int n0 = blockIdx.x * 64;
    const int c0 = blockIdx.y * 64;
    const int b = blockIdx.z;
    __shared__ float tile[64][65];
    const size_t sb = ((size_t)b * NCH + c0) * NPIX + n0;
#pragma unroll
    for (int i = 0; i < 16; ++i) {
        int idx = tid + i * 256;
        int r = idx >> 6, c = idx & 63;
        tile[r][c] = s1[sb + (size_t)r * NPIX + c];
    }
    __syncthreads();
#pragma unroll
    for (int i = 0; i < 8; ++i) {
        int idx = tid + i * 256;
        int nn = idx >> 5, cp = (idx & 31) * 2;
        union { __bf16 h[2]; unsigned u; } pk;
        pk.h[0] = (__bf16)tile[cp][nn];
        pk.h[1] = (__bf16)tile[cp + 1][nn];
        *(unsigned*)&dst[((size_t)b * NPIX + n0 + nn) * NCH + c0 + cp] = pk.u;
    }
}

// ---------------- MFMA 1x1 conv: 16m x 16oc per wave, 1-wave WGs -------------
// grid (NPIX/16, OC/16, B), block 64.
// MODE 0: qk   -> Qb [bh][n][32] (scaled bf16, out_b) + Kf frag tiles (out_b2)
// MODE 1: v    -> out_f NCHW f32 + Vf frag tiles (out_b)
// MODE 2: proj -> +resid(NCHW f32); out_f NCHW f32 (x1) + out_b NHWC bf16 (x1)
// MODE 3: fc1  -> silu; out_b NHWC bf16
// MODE 4: fc2  -> +resid(NCHW f32); out_f NCHW f32 (final)
template <int IC, int OC, int MODE>
__global__ __launch_bounds__(64) void convmm_k(
    const __bf16* __restrict__ A, const __bf16* __restrict__ W,
    const float* __restrict__ bias, const float* __restrict__ resid,
    float* __restrict__ out_f, __bf16* __restrict__ out_b,
    __bf16* __restrict__ out_b2) {
    const int lane = threadIdx.x;
    const int l16 = lane & 15, quad = lane >> 4;
    const int m0 = blockIdx.x * 16;
    const int oc0 = blockIdx.y * 16;
    const int b = blockIdx.z;

    const __bf16* aptr = A + ((size_t)b * NPIX + m0 + l16) * IC + quad * 8;
    const __bf16* bptr = W + (size_t)(oc0 + l16) * IC + quad * 8;

    f32x4 acc = {0.f, 0.f, 0.f, 0.f};
#pragma unroll 8
    for (int k = 0; k < IC; k += 32) {
        bf16x8 af = *(const bf16x8*)(aptr + k);
        bf16x8 bf = *(const bf16x8*)(bptr + k);
        acc = __builtin_amdgcn_mfma_f32_16x16x32_bf16(af, bf, acc, 0, 0, 0);
    }

    const int oc = oc0 + l16;
    const int mb = m0 + quad * 4;
    const float bb = bias[oc];

    if constexpr (MODE == 0) {
        const int h = oc0 >> 6;
        const int bh = b * NHD + h;
        const int dd = (oc0 & 16) + l16;
        if ((oc0 & 32) == 0) {
            // Q: scale folds hd^-0.5 * log2(e)
            const float qs = 0.17677669529663689f * 1.4426950408889634f;
#pragma unroll
            for (int r = 0; r < 4; ++r)
                out_b[((size_t)bh * NPIX + mb + r) * 32 + dd] = (__bf16)((acc[r] + bb) * qs);
        } else {
            // Kf tile T=m0>>4: element(lane=(dq,key&15), j=dd&7) = K[key][dd]
            __bf16* kp = out_b2 + ((size_t)(bh * 144 + (m0 >> 4)) * 64 + (dd >> 3) * 16 + quad * 4) * 8 + (dd & 7);
#pragma unroll
            for (int r = 0; r < 4; ++r) kp[r * 8] = (__bf16)(acc[r] + bb);
        }
    } else if constexpr (MODE == 1) {
        const int h = oc0 >> 5;
        const int bh = b * NHD + h;
        const int half = (oc0 >> 4) & 1;
        const size_t fb = ((size_t)b * OC + oc) * NPIX + mb;
        float4 vf_; float* vp = &vf_.x;
        union { __bf16 hh[4]; uint2 u; } pk;
#pragma unroll
        for (int r = 0; r < 4; ++r) {
            float v = acc[r] + bb;
            vp[r] = v; pk.hh[r] = (__bf16)v;
        }
        *(float4*)&out_f[fb] = vf_;
        // Vf tile T=m0>>4: lane holds [V[l16][16T+4q+r] | V[16+l16][...]]; 8B store
        *(uint2*)&out_b[((size_t)(bh * 144 + (m0 >> 4)) * 64 + lane) * 8 + half * 4] = pk.u;
    } else if constexpr (MODE == 2) {
        const size_t fb = ((size_t)b * OC + oc) * NPIX + mb;
        float4 xr = *(const float4*)&resid[fb];
        const float* xp = &xr.x;
        float4 vf_; float* vp = &vf_.x;
#pragma unroll
        for (int r = 0; r < 4; ++r) {
            float v = acc[r] + bb + xp[r];
            vp[r] = v;
            out_b[((size_t)b * NPIX + mb + r) * OC + oc] = (__bf16)v;
        }
        *(float4*)&out_f[fb] = vf_;
    } else if constexpr (MODE == 3) {
#pragma unroll
        for (int r = 0; r < 4; ++r) {
            float v = acc[r] + bb;
            v = v / (1.f + __expf(-v));
            out_b[((size_t)b * NPIX + mb + r) * OC + oc] = (__bf16)v;
        }
    } else {  // MODE 4
        const size_t fb = ((size_t)b * OC + oc) * NPIX + mb;
        float4 xr = *(const float4*)&resid[fb];
        const float* xp = &xr.x;
        float4 vf_; float* vp = &vf_.x;
#pragma unroll
        for (int r = 0; r < 4; ++r) vp[r] = acc[r] + bb + xp[r];
        *(float4*)&out_f[fb] = vf_;
    }
}

// ---------------- depthwise 7x7, SAME, per (b,c) plane ----------------
__global__ __launch_bounds__(256) void dwconv_k(const float* __restrict__ vb,
                                                const float* __restrict__ pw,
                                                const float* __restrict__ pb,
                                                float* __restrict__ pe) {
    const int c = blockIdx.x, b = blockIdx.y, tid = threadIdx.x;
    __shared__ float plane[NPIX];
    __shared__ float wk[49];
    const size_t base = ((size_t)b * NCH + c) * NPIX;
    for (int i = tid; i < NPIX; i += 256) plane[i] = vb[base + i];
    if (tid < 49) wk[tid] = pw[c * 49 + tid];
    float bb = pb[c];
    __syncthreads();
    for (int p = tid; p < NPIX; p += 256) {
        int y = p / 48, x = p - y * 48;
        float s = bb;
#pragma unroll
        for (int ky = 0; ky < 7; ++ky) {
            int yy = y + ky - 3;
            if ((unsigned)yy < 48u) {
#pragma unroll
                for (int kx = 0; kx < 7; ++kx) {
                    int xx = x + kx - 3;
                    if ((unsigned)xx < 48u) s += wk[ky * 7 + kx] * plane[yy * 48 + xx];
                }
            }
        }
        pe[base + p] = s;
    }
}

// ---------------- MFMA flash attention v4 ----------------
// 32 queries/wave (2 B-frags), key-split 4 (36 tiles each), zero-pad dual-B
// PV (one va load feeds both d-halves). No LDS, no barriers, no running max.
// grid (NPIX/128, NH, B*4): z -> b=z>>2, ks=z&3.
__global__ __launch_bounds__(256) void attn_mfma4_k(const __bf16* __restrict__ Qb,
                                                    const __bf16* __restrict__ Kf,
                                                    const __bf16* __restrict__ Vf,
                                                    float* __restrict__ opart,
                                                    float* __restrict__ lpart) {
    const int tid = threadIdx.x;
    const int wave = tid >> 6, lane = tid & 63;
    const int l16 = lane & 15, quad = lane >> 4;
    const int nb = blockIdx.x * 128;
    const int h = blockIdx.y;
    const int b = blockIdx.z >> 2, ks = blockIdx.z & 3;
    const int bh = b * NHD + h;
    const int qb = nb + wave * 32;

    bf16x8 b_q0 = *(const bf16x8*)(Qb + ((size_t)bh * NPIX + qb + l16) * 32 + quad * 8);
    bf16x8 b_q1 = *(const bf16x8*)(Qb + ((size_t)bh * NPIX + qb + 16 + l16) * 32 + quad * 8);

    const __bf16* kf = Kf + ((size_t)(bh * 144 + ks * 36) * 64 + lane) * 8;
    const __bf16* vf = Vf + ((size_t)(bh * 144 + ks * 36) * 64 + lane) * 8;

    f32x4 o00 = {0.f,0.f,0.f,0.f}, o01 = {0.f,0.f,0.f,0.f};
    f32x4 o10 = {0.f,0.f,0.f,0.f}, o11 = {0.f,0.f,0.f,0.f};
    f32x4 l0 = {0.f,0.f,0.f,0.f}, l1 = {0.f,0.f,0.f,0.f};

#pragma unroll 3
    for (int t = 0; t < 36; ++t) {
        bf16x8 a_k = *(const bf16x8*)(kf + (size_t)t * 512);
        bf16x8 va  = *(const bf16x8*)(vf + (size_t)t * 512);
        f32x4 z = {0.f, 0.f, 0.f, 0.f};
        f32x4 s0 = __builtin_amdgcn_mfma_f32_16x16x32_bf16(a_k, b_q0, z, 0, 0, 0);
        f32x4 s1 = __builtin_amdgcn_mfma_f32_16x16x32_bf16(a_k, b_q1, z, 0, 0, 0);
        f32x4 p0, p1;
#pragma unroll
        for (int r = 0; r < 4; ++r) {
            p0[r] = __builtin_amdgcn_exp2f(s0[r]);
            p1[r] = __builtin_amdgcn_exp2f(s1[r]);
        }
        l0 += p0; l1 += p1;
        bf16x8 b0lo = {}, b0hi = {}, b1lo = {}, b1hi = {};
#pragma unroll
        for (int r = 0; r < 4; ++r) {
            __bf16 c0 = (__bf16)p0[r], c1 = (__bf16)p1[r];
            b0lo[r] = c0; b0hi[4 + r] = c0;
            b1lo[r] = c1; b1hi[4 + r] = c1;
        }
        o00 = __builtin_amdgcn_mfma_f32_16x16x32_bf16(va, b0lo, o00, 0, 0, 0);
        o01 = __builtin_amdgcn_mfma_f32_16x16x32_bf16(va, b0hi, o01, 0, 0, 0);
        o10 = __builtin_amdgcn_mfma_f32_16x16x32_bf16(va, b1lo, o10, 0, 0, 0);
        o11 = __builtin_amdgcn_mfma_f32_16x16x32_bf16(va, b1hi, o11, 0, 0, 0);
    }

    float ls0 = l0[0] + l0[1] + l0[2] + l0[3];
    ls0 += __shfl_xor(ls0, 16); ls0 += __shfl_xor(ls0, 32);
    float ls1 = l1[0] + l1[1] + l1[2] + l1[3];
    ls1 += __shfl_xor(ls1, 16); ls1 += __shfl_xor(ls1, 32);

    float* op = opart + (size_t)(ks * 16 + bh) * 32 * NPIX;
    const int n0 = qb + l16, n1 = qb + 16 + l16;
#pragma unroll
    for (int r = 0; r < 4; ++r) {
        op[(size_t)(quad * 4 + r) * NPIX + n0]      = o00[r];
        op[(size_t)(16 + quad * 4 + r) * NPIX + n0] = o01[r];
        op[(size_t)(quad * 4 + r) * NPIX + n1]      = o10[r];
        op[(size_t)(16 + quad * 4 + r) * NPIX + n1] = o11[r];
    }
    if (quad == 0) {
        lpart[(size_t)(ks * 16 + bh) * NPIX + n0] = ls0;
        lpart[(size_t)(ks * 16 + bh) * NPIX + n1] = ls1;
    }
}

// ---------------- merge 4 splits + normalize + add pe -> NHWC bf16 -----------
// grid (NPIX/64, NH, B), block 256
__global__ __launch_bounds__(256) void merge2_k(const float* __restrict__ opart,
                                                const float* __restrict__ lpart,
                                                const float* __restrict__ pe,
                                                __bf16* __restrict__ opb) {
    const int tid = threadIdx.x;
    const int n0 = blockIdx.x * 64;
    const int h = blockIdx.y, b = blockIdx.z;
    const int bh = b * NHD + h;

    __shared__ float tinv[64];
    __shared__ float tile[64][33];

    if (tid < 64) {
        const int n = n0 + tid;
        float l = 0.f;
#pragma unroll
        for (int s = 0; s < 4; ++s) l += lpart[(size_t)(s * 16 + bh) * NPIX + n];
        tinv[tid] = 1.f / l;
    }
    __syncthreads();

#pragma unroll
    for (int pass = 0; pass < 8; ++pass) {
        const int idx = pass * 256 + tid;
        const int d = idx >> 6, c = idx & 63;
        float v = 0.f;
#pragma unroll
        for (int s = 0; s < 4; ++s)
            v += opart[((size_t)(s * 16 + bh) * 32 + d) * NPIX + n0 + c];
        v = v * tinv[c] + pe[((size_t)(b * NCH + h * HD + d)) * NPIX + n0 + c];
        tile[c][d] = v;
    }
    __syncthreads();

    const int n = tid >> 2, j = tid & 3;
    union { __bf16 hh[8]; uint4 u; } pk;
#pragma unroll
    for (int e = 0; e < 8; ++e) pk.hh[e] = (__bf16)tile[n][j * 8 + e];
    *(uint4*)&opb[((size_t)(b * NPIX + n0 + n)) * NCH + h * HD + j * 8] = pk.u;
}

extern "C" void kernel_launch(void* const* d_in, const int* in_sizes, int n_in,
                              void* d_out, int out_size, void* d_ws, size_t ws_size,
                              hipStream_t stream) {
    const float* x    = (const float*)d_in[0];
    const float* qk_w = (const float*)d_in[1];
    const float* qk_b = (const float*)d_in[2];
    const float* v_w  = (const float*)d_in[3];
    const float* v_b  = (const float*)d_in[4];
    const float* pe_w = (const float*)d_in[5];
    const float* pe_b = (const float*)d_in[6];
    const float* pj_w = (const float*)d_in[7];
    const float* pj_b = (const float*)d_in[8];
    const float* f1_w = (const float*)d_in[9];
    const float* f1_b = (const float*)d_in[10];
    const float* f2_w = (const float*)d_in[11];
    const float* f2_b = (const float*)d_in[12];
    float* out = (float*)d_out;

    const int B = 2;
    const size_t plane = (size_t)NCH * NPIX;       // 589824
    const size_t bp = (size_t)B * plane;           // 1179648

    float* v_bu  = (float*)d_ws;                   // NCHW f32
    float* pe_bu = v_bu + bp;
    float* x1_f  = pe_bu + bp;
    float* opart = x1_f + bp;                      // 4*bp f32
    float* lpart = opart + 4 * bp;                 // 64*2304 = 147456 f32
    __bf16* Xb   = (__bf16*)(lpart + 147456);      // NHWC bf16 [b][n][256]
    __bf16* opb  = Xb + bp;                        // NHWC bf16 (o/l + pe)
    __bf16* x1b  = opb + bp;                       // NHWC bf16
    __bf16* hb   = x1b + bp;                       // NHWC bf16 [b][n][512]
    __bf16* Qb   = hb + 2 * bp;                    // [bh][n][32] (pre-scaled)
    __bf16* Kf   = Qb + bp;                        // QK A-frag tiles
    __bf16* Vf   = Kf + bp;                        // PV A-frag tiles
    __bf16* Wall = Vf + bp;                        // 524288 bf16
    __bf16* Wq = Wall;
    __bf16* Wv = Wall + 131072;
    __bf16* Wp = Wall + 196608;
    __bf16* W1 = Wall + 262144;
    __bf16* W2 = Wall + 393216;

    wcast_k<<<512, 256, 0, stream>>>(qk_w, v_w, pj_w, f1_w, f2_w, Wall);
    nchw2nhwc_k<<<dim3(NPIX / 64, 4, B), 256, 0, stream>>>(x, Xb);
    // qk conv -> Qb + Kf directly
    convmm_k<256, 512, 0><<<dim3(NPIX / 16, 32, B), 64, 0, stream>>>(
        Xb, Wq, qk_b, nullptr, nullptr, Qb, Kf);
    // v conv -> NCHW f32 (for dwconv) + Vf directly
    convmm_k<256, 256, 1><<<dim3(NPIX / 16, 16, B), 64, 0, stream>>>(
        Xb, Wv, v_b, nullptr, v_bu, Vf, nullptr);
    // pe = dwconv7x7(v_full) + pe_b
    dwconv_k<<<dim3(NCH, B), 256, 0, stream>>>(v_bu, pe_w, pe_b, pe_bu);
    // attention partials (key-split 4)
    attn_mfma4_k<<<dim3(NPIX / 128, NHD, B * 4), 256, 0, stream>>>(Qb, Kf, Vf, opart, lpart);
    // merge + normalize + pe add -> NHWC bf16
    merge2_k<<<dim3(NPIX / 64, NHD, B), 256, 0, stream>>>(opart, lpart, pe_bu, opb);
    // x1 = x + proj(o+pe): NCHW f32 + NHWC bf16
    convmm_k<256, 256, 2><<<dim3(NPIX / 16, 16, B), 64, 0, stream>>>(
        opb, Wp, pj_b, x, x1_f, x1b, nullptr);
    // h = silu(fc1(x1)) -> NHWC bf16
    convmm_k<256, 512, 3><<<dim3(NPIX / 16, 32, B), 64, 0, stream>>>(
        x1b, W1, f1_b, nullptr, nullptr, hb, nullptr);
    // out = x1 + fc2(h) -> NCHW f32
    convmm_k<512, 256, 4><<<dim3(NPIX / 16, 16, B), 64, 0, stream>>>(
        hb, W2, f2_b, x1_f, out, nullptr, nullptr);
}